// Round 9
// baseline (259.849 us; speedup 1.0000x reference)
//
#include <hip/hip_runtime.h>
#include <hip/hip_bf16.h>

#define NN 6144
#define FEATN 128
#define INSM 512
#define HIDN 256
#define DOUT 64

typedef _Float16 h4v __attribute__((ext_vector_type(4)));
typedef _Float16 h8v __attribute__((ext_vector_type(8)));
typedef float f32x4 __attribute__((ext_vector_type(4)));

// Weight-pack offsets (in halves) inside the contiguous wpk buffer.
#define O_W0L 0
#define O_W0S 65536
#define O_W0H 327680
#define O_W1L 589824
#define O_W1S 622592
#define O_W1H 655360
#define WPK_HALVES 688128

// ---------------------------------------------------------------------------
// Pack the 6 weight matrices to fp16 hi/lo in MFMA B-fragment k-major layout.
// ---------------------------------------------------------------------------
__global__ __launch_bounds__(256) void pack_w_kernel(
    const float* __restrict__ W0l, const float* __restrict__ W0s_,
    const float* __restrict__ W0h, const float* __restrict__ W1l,
    const float* __restrict__ W1s_, const float* __restrict__ W1h,
    _Float16* __restrict__ pk)
{
    const int id = blockIdx.y;
    const float* src; int K, N, offhi;
    switch (id) {
        case 0:  src = W0l;  K = 128; N = 256; offhi = O_W0L; break;
        case 1:  src = W0s_; K = 512; N = 256; offhi = O_W0S; break;
        case 2:  src = W0h;  K = 512; N = 256; offhi = O_W0H; break;
        case 3:  src = W1l;  K = 256; N = 64;  offhi = O_W1L; break;
        case 4:  src = W1s_; K = 256; N = 64;  offhi = O_W1S; break;
        default: src = W1h;  K = 256; N = 64;  offhi = O_W1H; break;
    }
    const int cnt = (K * N) >> 3;
    const int idx = blockIdx.x * 256 + threadIdx.x;
    if (idx >= cnt) return;
    const int col  = (N == 256) ? (idx & 255) : (idx & 63);
    const int kblk = (N == 256) ? (idx >> 8) : (idx >> 6);
    h8v hi, lo;
    #pragma unroll
    for (int e = 0; e < 8; ++e) {
        float x = src[(size_t)(kblk * 8 + e) * N + col];
        _Float16 h = (_Float16)x;
        hi[e] = h;
        lo[e] = (_Float16)(x - (float)h);
    }
    *reinterpret_cast<h8v*>(&pk[(size_t)offhi + (size_t)idx * 8]) = hi;
    *reinterpret_cast<h8v*>(&pk[(size_t)offhi + (size_t)(K * N) + (size_t)idx * 8]) = lo;
}

// ---------------------------------------------------------------------------
// MFMA MLP (proven round 8): all three branches; br2 -> emb, ut.
// ---------------------------------------------------------------------------
__global__ __launch_bounds__(256) void mlp2_kernel(
    const float* __restrict__ ori, const float* __restrict__ sm,
    const _Float16* __restrict__ pk,
    const float* __restrict__ b0l, const float* __restrict__ b0s,
    const float* __restrict__ b0h, const float* __restrict__ b1l,
    const float* __restrict__ b1s, const float* __restrict__ b1h,
    const float* __restrict__ am_p, const float* __restrict__ ah_p,
    float* __restrict__ out, float* __restrict__ emb, float* __restrict__ ut)
{
    __shared__ __align__(16) char smem[64 * 264 * 4];
    float* xs   = (float*)smem;
    float* hs   = (float*)smem;
    float* vals = (float*)smem;

    const int t = threadIdx.x;
    const int br = blockIdx.y;
    const int r0 = blockIdx.x * 64;
    const int w = t >> 6, lane = t & 63, arow = lane & 15, ag = lane >> 4;

    const float* X;
    const _Float16 *B0hi, *B0lo, *B1hi, *B1lo;
    const float *bias0, *bias1;
    int K1; float alpha;
    if (br == 0) {
        X = ori; B0hi = pk + O_W0L; B0lo = B0hi + 128 * 256;
        B1hi = pk + O_W1L; B1lo = B1hi + 256 * 64;
        bias0 = b0l; bias1 = b1l; K1 = FEATN; alpha = am_p[0];
    } else if (br == 1) {
        X = sm; B0hi = pk + O_W0S; B0lo = B0hi + 512 * 256;
        B1hi = pk + O_W1S; B1lo = B1hi + 256 * 64;
        bias0 = b0s; bias1 = b1s; K1 = INSM; alpha = am_p[0];
    } else {
        X = sm; B0hi = pk + O_W0H; B0lo = B0hi + 512 * 256;
        B1hi = pk + O_W1H; B1lo = B1hi + 256 * 64;
        bias0 = b0h; bias1 = b1h; K1 = INSM; alpha = ah_p[0];
    }
    const int nks = K1 >> 5;

    const int srow = t >> 2, sseg = t & 3;
    const float* Xrow = X + (size_t)(r0 + srow) * K1 + sseg * 8;

    {
        float4 a = *reinterpret_cast<const float4*>(Xrow);
        float4 b = *reinterpret_cast<const float4*>(Xrow + 4);
        float* p = &xs[(0 * 64 + srow) * 32 + sseg * 8];
        *reinterpret_cast<float4*>(p) = a;
        *reinterpret_cast<float4*>(p + 4) = b;
    }
    __syncthreads();

    f32x4 acc1[4][4] = {};
    for (int ks = 0; ks < nks; ++ks) {
        const int buf = ks & 1;
        if (ks + 1 < nks) {
            const float* g = Xrow + (ks + 1) * 32;
            float4 a = *reinterpret_cast<const float4*>(g);
            float4 b = *reinterpret_cast<const float4*>(g + 4);
            float* p = &xs[((buf ^ 1) * 64 + srow) * 32 + sseg * 8];
            *reinterpret_cast<float4*>(p) = a;
            *reinterpret_cast<float4*>(p + 4) = b;
        }
        h8v ahi[4], alo[4];
        #pragma unroll
        for (int rt = 0; rt < 4; ++rt) {
            const float* ap = &xs[(buf * 64 + rt * 16 + arow) * 32 + ag * 8];
            float4 a = *reinterpret_cast<const float4*>(ap);
            float4 b = *reinterpret_cast<const float4*>(ap + 4);
            float fv[8] = {a.x, a.y, a.z, a.w, b.x, b.y, b.z, b.w};
            #pragma unroll
            for (int e = 0; e < 8; ++e) {
                _Float16 h = (_Float16)fv[e];
                ahi[rt][e] = h;
                alo[rt][e] = (_Float16)(fv[e] - (float)h);
            }
        }
        #pragma unroll
        for (int ct = 0; ct < 4; ++ct) {
            const size_t bidx =
                ((size_t)(ks * 4 + ag) * 256 + w * 64 + ct * 16 + arow) * 8;
            h8v bhi = *reinterpret_cast<const h8v*>(&B0hi[bidx]);
            h8v blo = *reinterpret_cast<const h8v*>(&B0lo[bidx]);
            #pragma unroll
            for (int rt = 0; rt < 4; ++rt) {
                acc1[rt][ct] = __builtin_amdgcn_mfma_f32_16x16x32_f16(ahi[rt], bhi, acc1[rt][ct], 0, 0, 0);
                acc1[rt][ct] = __builtin_amdgcn_mfma_f32_16x16x32_f16(ahi[rt], blo, acc1[rt][ct], 0, 0, 0);
                acc1[rt][ct] = __builtin_amdgcn_mfma_f32_16x16x32_f16(alo[rt], bhi, acc1[rt][ct], 0, 0, 0);
            }
        }
        __syncthreads();
    }

    #pragma unroll
    for (int ct = 0; ct < 4; ++ct) {
        const int col = w * 64 + ct * 16 + arow;
        const float bb = bias0[col];
        #pragma unroll
        for (int rt = 0; rt < 4; ++rt)
            #pragma unroll
            for (int r = 0; r < 4; ++r) {
                float h = acc1[rt][ct][r] + bb;
                hs[(rt * 16 + ag * 4 + r) * 264 + col] = (h >= 0.f) ? h : alpha * h;
            }
    }
    __syncthreads();

    f32x4 acc2[4] = {};
    #pragma unroll
    for (int ks2 = 0; ks2 < 8; ++ks2) {
        const size_t bidx = ((size_t)(ks2 * 4 + ag) * 64 + w * 16 + arow) * 8;
        h8v bhi = *reinterpret_cast<const h8v*>(&B1hi[bidx]);
        h8v blo = *reinterpret_cast<const h8v*>(&B1lo[bidx]);
        #pragma unroll
        for (int rt = 0; rt < 4; ++rt) {
            const float* ap = &hs[(rt * 16 + arow) * 264 + ks2 * 32 + ag * 8];
            float4 a = *reinterpret_cast<const float4*>(ap);
            float4 b = *reinterpret_cast<const float4*>(ap + 4);
            float fv[8] = {a.x, a.y, a.z, a.w, b.x, b.y, b.z, b.w};
            h8v ahi8, alo8;
            #pragma unroll
            for (int e = 0; e < 8; ++e) {
                _Float16 h = (_Float16)fv[e];
                ahi8[e] = h;
                alo8[e] = (_Float16)(fv[e] - (float)h);
            }
            acc2[rt] = __builtin_amdgcn_mfma_f32_16x16x32_f16(ahi8, bhi, acc2[rt], 0, 0, 0);
            acc2[rt] = __builtin_amdgcn_mfma_f32_16x16x32_f16(ahi8, blo, acc2[rt], 0, 0, 0);
            acc2[rt] = __builtin_amdgcn_mfma_f32_16x16x32_f16(alo8, bhi, acc2[rt], 0, 0, 0);
        }
    }

    const int col2 = w * 16 + arow;
    const float bb1 = bias1[col2];
    if (br < 2) {
        float* dst = out + (size_t)br * NN * DOUT;
        #pragma unroll
        for (int rt = 0; rt < 4; ++rt)
            #pragma unroll
            for (int r = 0; r < 4; ++r)
                dst[(size_t)(r0 + rt * 16 + ag * 4 + r) * 64 + col2] =
                    acc2[rt][r] + bb1;
    } else {
        __syncthreads();
        #pragma unroll
        for (int rt = 0; rt < 4; ++rt)
            #pragma unroll
            for (int r = 0; r < 4; ++r)
                vals[(rt * 16 + ag * 4 + r) * 65 + col2] = acc2[rt][r] + bb1;
        __syncthreads();
        for (int rr = 0; rr < 16; ++rr) {
            const int row = w * 16 + rr;
            float v = vals[row * 65 + lane];
            float mv = v;
            for (int off = 32; off > 0; off >>= 1) mv = fmaxf(mv, __shfl_xor(mv, off));
            float e = expf(v - mv);
            float ssum = e;
            for (int off = 32; off > 0; off >>= 1) ssum += __shfl_xor(ssum, off);
            float s = e / ssum;
            float n2 = s * s;
            for (int off = 32; off > 0; off >>= 1) n2 += __shfl_xor(n2, off);
            float uu = s * rsqrtf(n2);
            emb[(size_t)(r0 + row) * 64 + lane] = v;
            ut[(size_t)lane * NN + (r0 + row)] = uu;
        }
    }
}

// ---------------------------------------------------------------------------
// Column sums of u (= row sums of ut) in f64.
// ---------------------------------------------------------------------------
__global__ __launch_bounds__(256) void colsum_kernel(const float* __restrict__ ut,
                                                     double* __restrict__ colsum)
{
    __shared__ double cred[4];
    const int c = blockIdx.x, t = threadIdx.x;
    double a = 0.0;
    for (int i = t; i < NN; i += 256) a += (double)ut[(size_t)c * NN + i];
    for (int off = 32; off > 0; off >>= 1) a += __shfl_xor(a, off);
    if ((t & 63) == 0) cred[t >> 6] = a;
    __syncthreads();
    if (t == 0) colsum[c] = cred[0] + cred[1] + cred[2] + cred[3];
}

// ---------------------------------------------------------------------------
// emb -> fp16 hi/lo, k-major packed for MFMA B-fragments.
// ---------------------------------------------------------------------------
__global__ __launch_bounds__(256) void emb_split_kernel(
    const float* __restrict__ emb, _Float16* __restrict__ ehi,
    _Float16* __restrict__ elo)
{
    const int idx = blockIdx.x * 256 + threadIdx.x;
    const int c = idx & 63, jblk = idx >> 6;
    h8v hi, lo;
    #pragma unroll
    for (int e = 0; e < 8; ++e) {
        float x = emb[(size_t)(jblk * 8 + e) * 64 + c];
        _Float16 h = (_Float16)x;
        hi[e] = h;
        lo[e] = (_Float16)(x - (float)h);
    }
    *reinterpret_cast<h8v*>(&ehi[(size_t)idx * 8]) = hi;
    *reinterpret_cast<h8v*>(&elo[(size_t)idx * 8]) = lo;
}

// ---------------------------------------------------------------------------
// ut -> fp16 hi/lo, packed as MFMA B-fragments for R = u u^T:
// B[k][j] = ut[k][j] -> pk[(kblk*NN + j)*8 + (k&7)].
// ---------------------------------------------------------------------------
__global__ __launch_bounds__(256) void ut_split_kernel(
    const float* __restrict__ ut, _Float16* __restrict__ phi,
    _Float16* __restrict__ plo)
{
    const int j = blockIdx.x * 256 + threadIdx.x;     // 0..NN
    const int kblk = blockIdx.y;                      // 0..7
    h8v hi, lo;
    #pragma unroll
    for (int e = 0; e < 8; ++e) {
        float x = ut[(size_t)(kblk * 8 + e) * NN + j];
        _Float16 h = (_Float16)x;
        hi[e] = h;
        lo[e] = (_Float16)(x - (float)h);
    }
    const size_t o = ((size_t)kblk * NN + j) * 8;
    *reinterpret_cast<h8v*>(&phi[o]) = hi;
    *reinterpret_cast<h8v*>(&plo[o]) = lo;
}

// ---------------------------------------------------------------------------
// MFMA max pass: max_{i!=j} R_ij over upper-triangle 64x64 tiles.
// A-frags from LDS-staged f32 ut rows (split in-register); B from utpk (L2).
// ---------------------------------------------------------------------------
__global__ __launch_bounds__(256) void max4_kernel(
    const float* __restrict__ ut, const _Float16* __restrict__ uphi,
    const _Float16* __restrict__ uplo, unsigned int* __restrict__ mx)
{
    const int ti = blockIdx.x, tj = blockIdx.y;
    if (tj < ti) return;
    __shared__ float uis[64 * 68];
    __shared__ float red[4];
    const int t = threadIdx.x;
    {   // stage uis[r][k] = ut[k][ti*64+r]; 4 coalesced loads -> 1 b128 write
        const int r = t & 63, kb = t >> 6;        // kb 0..3
        #pragma unroll
        for (int kk = 0; kk < 4; ++kk) {
            const int k0 = (kb + kk * 4) * 4;
            float4 v;
            v.x = ut[(size_t)(k0 + 0) * NN + ti * 64 + r];
            v.y = ut[(size_t)(k0 + 1) * NN + ti * 64 + r];
            v.z = ut[(size_t)(k0 + 2) * NN + ti * 64 + r];
            v.w = ut[(size_t)(k0 + 3) * NN + ti * 64 + r];
            *reinterpret_cast<float4*>(&uis[r * 68 + k0]) = v;
        }
    }
    __syncthreads();
    const int w = t >> 6, l = t & 63, arow = l & 15, ag = l >> 4;
    h8v ahi[4][2], alo[4][2];
    #pragma unroll
    for (int rt = 0; rt < 4; ++rt)
        #pragma unroll
        for (int ks = 0; ks < 2; ++ks) {
            const float* ap = &uis[(rt * 16 + arow) * 68 + ks * 32 + ag * 8];
            float4 a = *reinterpret_cast<const float4*>(ap);
            float4 b = *reinterpret_cast<const float4*>(ap + 4);
            float fv[8] = {a.x, a.y, a.z, a.w, b.x, b.y, b.z, b.w};
            #pragma unroll
            for (int e = 0; e < 8; ++e) {
                _Float16 h = (_Float16)fv[e];
                ahi[rt][ks][e] = h;
                alo[rt][ks][e] = (_Float16)(fv[e] - (float)h);
            }
        }
    f32x4 acc[4] = {};
    #pragma unroll
    for (int ks = 0; ks < 2; ++ks) {
        const size_t bidx = ((size_t)(ks * 4 + ag) * NN + tj * 64 + w * 16 + arow) * 8;
        h8v bhi = *reinterpret_cast<const h8v*>(&uphi[bidx]);
        h8v blo = *reinterpret_cast<const h8v*>(&uplo[bidx]);
        #pragma unroll
        for (int rt = 0; rt < 4; ++rt) {
            acc[rt] = __builtin_amdgcn_mfma_f32_16x16x32_f16(ahi[rt][ks], bhi, acc[rt], 0, 0, 0);
            acc[rt] = __builtin_amdgcn_mfma_f32_16x16x32_f16(ahi[rt][ks], blo, acc[rt], 0, 0, 0);
            acc[rt] = __builtin_amdgcn_mfma_f32_16x16x32_f16(alo[rt][ks], bhi, acc[rt], 0, 0, 0);
        }
    }
    float lm = 0.f;
    const int gj = tj * 64 + w * 16 + arow;
    #pragma unroll
    for (int rt = 0; rt < 4; ++rt)
        #pragma unroll
        for (int r = 0; r < 4; ++r) {
            const int gi = ti * 64 + rt * 16 + ag * 4 + r;
            if (gi != gj) lm = fmaxf(lm, acc[rt][r]);
        }
    for (int off = 32; off > 0; off >>= 1) lm = fmaxf(lm, __shfl_xor(lm, off));
    if ((t & 63) == 0) red[t >> 6] = lm;
    __syncthreads();
    if (t == 0) {
        float bm = fmaxf(fmaxf(red[0], red[1]), fmaxf(red[2], red[3]));
        atomicMax(mx, __float_as_uint(bm));   // all candidates > 0
    }
}

__global__ void finalize_kernel(const double* __restrict__ colsum,
                                const unsigned int* __restrict__ mx,
                                float* __restrict__ scal)
{
    const int c = threadIdx.x;
    double cs = colsum[c];
    double s2 = cs * cs;
    for (int off = 32; off > 0; off >>= 1) s2 += __shfl_xor(s2, off);
    if (c == 0) {
        double md = (s2 - (double)NN) / ((double)NN * (double)NN);
        float mf = (float)md;
        float mxv = __uint_as_float(mx[0]);
        scal[0] = mf;
        scal[1] = 1.0f / (mxv - mf);
        scal[2] = 1.0f / mf;
    }
}

// ---------------------------------------------------------------------------
// Fully fused propagation: R computed in-register via MFMA (never stored).
// 384 blocks x 16 rows, 4 waves. Per 64-j tile:
//   R-frag (6 MFMA, A=u rows in regs, B=utpk from L2) -> transform ->
//   v/p hi/lo scalar writes into swizzled Abuf -> barrier ->
//   prop3's proven consumer (12 MFMA: P and L logit GEMMs).
// Epilogue: N = P - (1+alpha)L, cross-wave softmax, f32 out.
// ---------------------------------------------------------------------------
__global__ __launch_bounds__(256) void prop4_kernel(
    const float* __restrict__ ut,
    const _Float16* __restrict__ uphi, const _Float16* __restrict__ uplo,
    const float* __restrict__ emb,
    const _Float16* __restrict__ ehi, const _Float16* __restrict__ elo,
    const float* __restrict__ scal, const float* __restrict__ ah_p,
    float* __restrict__ out3)
{
    __shared__ float uis[16 * 68];                       // 4.25 KB
    __shared__ __align__(16) _Float16 Abuf[2][4][1024];  // 16 KB
    __shared__ float smx[2][16][68];                     // 8.5 KB

    const int t = threadIdx.x;
    const int bi = blockIdx.x;
    const int gi0 = bi * 16;
    const float m = scal[0], inv_pd = scal[1], inv_m = scal[2];
    const float alpha = ah_p[0];

    {   // stage uis[r][k] = ut[k][gi0+r]
        const int r = t & 15, kb = t >> 4;               // kb 0..15
        const int k0 = kb * 4;
        float4 v;
        v.x = ut[(size_t)(k0 + 0) * NN + gi0 + r];
        v.y = ut[(size_t)(k0 + 1) * NN + gi0 + r];
        v.z = ut[(size_t)(k0 + 2) * NN + gi0 + r];
        v.w = ut[(size_t)(k0 + 3) * NN + gi0 + r];
        *reinterpret_cast<float4*>(&uis[r * 68 + k0]) = v;
    }
    __syncthreads();

    const int w = t >> 6, l = t & 63, arow = l & 15, ag = l >> 4;
    const int col = w * 16 + arow;                       // j within tile
    const int gl = col >> 3;                             // Abuf granule
    const int b0 = (col & 7) << 1;                       // byte in granule

    // A-frags for R (16 u rows), built once: row=arow, k=ks*32+ag*8+e
    h8v uahi[2], ualo[2];
    #pragma unroll
    for (int ks = 0; ks < 2; ++ks) {
        const float* ap = &uis[arow * 68 + ks * 32 + ag * 8];
        float4 a = *reinterpret_cast<const float4*>(ap);
        float4 b = *reinterpret_cast<const float4*>(ap + 4);
        float fv[8] = {a.x, a.y, a.z, a.w, b.x, b.y, b.z, b.w};
        #pragma unroll
        for (int e = 0; e < 8; ++e) {
            _Float16 h = (_Float16)fv[e];
            uahi[ks][e] = h;
            ualo[ks][e] = (_Float16)(fv[e] - (float)h);
        }
    }

    f32x4 accP = {0.f, 0.f, 0.f, 0.f};
    f32x4 accL = {0.f, 0.f, 0.f, 0.f};

    for (int jt = 0; jt < 96; ++jt) {
        const int buf = jt & 1;
        // ---- producer: R-frag via MFMA, transform, Abuf write ----
        {
            f32x4 accR = {0.f, 0.f, 0.f, 0.f};
            #pragma unroll
            for (int ks = 0; ks < 2; ++ks) {
                const size_t bidx =
                    ((size_t)(ks * 4 + ag) * NN + jt * 64 + col) * 8;
                h8v bhi = *reinterpret_cast<const h8v*>(&uphi[bidx]);
                h8v blo = *reinterpret_cast<const h8v*>(&uplo[bidx]);
                accR = __builtin_amdgcn_mfma_f32_16x16x32_f16(uahi[ks], bhi, accR, 0, 0, 0);
                accR = __builtin_amdgcn_mfma_f32_16x16x32_f16(uahi[ks], blo, accR, 0, 0, 0);
                accR = __builtin_amdgcn_mfma_f32_16x16x32_f16(ualo[ks], bhi, accR, 0, 0, 0);
            }
            const int gjj = jt * 64 + col;
            char* base = (char*)&Abuf[buf][0][0];
            #pragma unroll
            for (int r = 0; r < 4; ++r) {
                const int row = ag * 4 + r;              // i within block
                const int gi = gi0 + row;
                float lre = (gi == gjj) ? 0.f : accR[r];
                float x = lre - m;
                float v = (x > 0.f) ? x * inv_pd : -(lre * inv_m);
                if (gi == gjj) v += 1.f;                 // add_diag after where
                float p = (v >= 0.f) ? v : alpha * v;
                _Float16 vh = (_Float16)v;
                _Float16 ph = (_Float16)p;
                _Float16 vl = (_Float16)(v - (float)vh);
                _Float16 pl = (_Float16)(p - (float)ph);
                const int byte = row * 128 + ((gl ^ (row & 7)) << 4) + b0;
                *reinterpret_cast<_Float16*>(base + byte) = vh;
                *reinterpret_cast<_Float16*>(base + 2048 + byte) = vl;
                *reinterpret_cast<_Float16*>(base + 4096 + byte) = ph;
                *reinterpret_cast<_Float16*>(base + 6144 + byte) = pl;
            }
        }
        __syncthreads();

        // ---- consumer: P/L logit MFMAs (prop3-proven) ----
        const char* cbase = (const char*)&Abuf[buf][0][0];
        #pragma unroll
        for (int ks = 0; ks < 2; ++ks) {
            const int abyte = arow * 128 + (((ks * 4 + ag) ^ (arow & 7)) << 4);
            h8v vhiF = *reinterpret_cast<const h8v*>(cbase + abyte);
            h8v vloF = *reinterpret_cast<const h8v*>(cbase + 2048 + abyte);
            h8v phiF = *reinterpret_cast<const h8v*>(cbase + 4096 + abyte);
            h8v ploF = *reinterpret_cast<const h8v*>(cbase + 6144 + abyte);
            const size_t bidx = ((size_t)(jt * 8 + ks * 4 + ag) * 64 + col) * 8;
            h8v Bhi = *reinterpret_cast<const h8v*>(&ehi[bidx]);
            h8v Blo = *reinterpret_cast<const h8v*>(&elo[bidx]);
            accP = __builtin_amdgcn_mfma_f32_16x16x32_f16(phiF, Bhi, accP, 0, 0, 0);
            accP = __builtin_amdgcn_mfma_f32_16x16x32_f16(phiF, Blo, accP, 0, 0, 0);
            accP = __builtin_amdgcn_mfma_f32_16x16x32_f16(ploF, Bhi, accP, 0, 0, 0);
            accL = __builtin_amdgcn_mfma_f32_16x16x32_f16(vhiF, Bhi, accL, 0, 0, 0);
            accL = __builtin_amdgcn_mfma_f32_16x16x32_f16(vhiF, Blo, accL, 0, 0, 0);
            accL = __builtin_amdgcn_mfma_f32_16x16x32_f16(vloF, Bhi, accL, 0, 0, 0);
        }
    }

    // ---- epilogue: N = P - (1+alpha) L, cross-wave softmax ----
    {
        const float one_pa = 1.f + alpha;
        #pragma unroll
        for (int r = 0; r < 4; ++r) {
            const int row = ag * 4 + r;
            smx[0][row][col] = accP[r];
            smx[1][row][col] = accP[r] - one_pa * accL[r];
        }
    }
    __syncthreads();
    #pragma unroll
    for (int rr = 0; rr < 4; ++rr) {
        const int row = w * 4 + rr;
        float zp = smx[0][row][l];
        float mp = zp;
        for (int off = 32; off > 0; off >>= 1) mp = fmaxf(mp, __shfl_xor(mp, off));
        float ep = __expf(zp - mp);
        float sump = ep;
        for (int off = 32; off > 0; off >>= 1) sump += __shfl_xor(sump, off);
        float pp = ep / sump;

        float zn = smx[1][row][l];
        float mn = zn;
        for (int off = 32; off > 0; off >>= 1) mn = fmaxf(mn, __shfl_xor(mn, off));
        float en = __expf(zn - mn);
        float sumn = en;
        for (int off = 32; off > 0; off >>= 1) sumn += __shfl_xor(sumn, off);
        float pn = en / sumn;

        const size_t gi = (size_t)gi0 + row;
        out3[gi * 64 + l] = 0.5f * (pp - pn + emb[gi * 64 + l]);
    }
}

extern "C" void kernel_launch(void* const* d_in, const int* in_sizes, int n_in,
                              void* d_out, int out_size, void* d_ws, size_t ws_size,
                              hipStream_t stream)
{
    (void)in_sizes; (void)n_in; (void)out_size; (void)ws_size;
    const float* ori = (const float*)d_in[0];
    const float* sm  = (const float*)d_in[1];
    // d_in[2] processed_feature: unused; d_in[3] universal_re: unused (BETA=0)
    const float* W0s = (const float*)d_in[4];
    const float* b0s = (const float*)d_in[5];
    const float* W1s = (const float*)d_in[6];
    const float* b1s = (const float*)d_in[7];
    const float* W0l = (const float*)d_in[8];
    const float* b0l = (const float*)d_in[9];
    const float* W1l = (const float*)d_in[10];
    const float* b1l = (const float*)d_in[11];
    const float* W0h = (const float*)d_in[12];
    const float* b0h = (const float*)d_in[13];
    const float* W1h = (const float*)d_in[14];
    const float* b1h = (const float*)d_in[15];
    const float* amp = (const float*)d_in[16];
    const float* ahp = (const float*)d_in[17];

    float* out = (float*)d_out;                       // f32 output (ref dtype)
    float* ws = (float*)d_ws;
    float* emb = ws;                                  // NN*64 f32
    float* ut  = ws + (size_t)NN * DOUT;              // 64*NN f32 (u transposed)
    double* colsum = (double*)(ws + (size_t)2 * NN * DOUT);   // 64 f64
    unsigned int* mx = (unsigned int*)(ws + (size_t)2 * NN * DOUT + 128);
    float* scal = ws + (size_t)2 * NN * DOUT + 128 + 4;       // 3 f32
    size_t eh_off = (((size_t)2 * NN * DOUT + 128 + 8) + 15) & ~(size_t)15;
    _Float16* ehi = (_Float16*)(ws + eh_off);                 // NN*64 halves
    _Float16* elo = ehi + (size_t)NN * DOUT;
    size_t up_off = eh_off + (size_t)NN * DOUT;               // f32 words
    _Float16* uphi = (_Float16*)(ws + up_off);                // NN*64 halves
    _Float16* uplo = uphi + (size_t)NN * DOUT;
    size_t wpk_off = up_off + (size_t)NN * DOUT;
    _Float16* wpk = (_Float16*)(ws + wpk_off);                // 688128 halves
    // total ws footprint ~7.7 MB

    hipMemsetAsync(mx, 0, 4, stream);
    pack_w_kernel<<<dim3(64, 6), 256, 0, stream>>>(W0l, W0s, W0h, W1l, W1s, W1h, wpk);
    mlp2_kernel<<<dim3(NN / 64, 3), 256, 0, stream>>>(
        ori, sm, wpk, b0l, b0s, b0h, b1l, b1s, b1h, amp, ahp, out, emb, ut);
    colsum_kernel<<<64, 256, 0, stream>>>(ut, colsum);
    emb_split_kernel<<<NN * DOUT / 8 / 256, 256, 0, stream>>>(emb, ehi, elo);
    ut_split_kernel<<<dim3(NN / 256, 8), 256, 0, stream>>>(ut, uphi, uplo);
    max4_kernel<<<dim3(96, 96), 256, 0, stream>>>(ut, uphi, uplo, mx);
    finalize_kernel<<<1, 64, 0, stream>>>(colsum, mx, scal);
    prop4_kernel<<<NN / 16, 256, 0, stream>>>(ut, uphi, uplo, emb, ehi, elo,
                                              scal, ahp,
                                              out + (size_t)2 * NN * DOUT);
}

// Round 10
// 208.311 us; speedup vs baseline: 1.2474x; 1.2474x over previous
//
#include <hip/hip_runtime.h>
#include <hip/hip_bf16.h>

#define NN 6144
#define FEATN 128
#define INSM 512
#define HIDN 256
#define DOUT 64

typedef _Float16 h4v __attribute__((ext_vector_type(4)));
typedef _Float16 h8v __attribute__((ext_vector_type(8)));
typedef float f32x4 __attribute__((ext_vector_type(4)));

// Weight-pack offsets (in halves) inside the contiguous wpk buffer.
#define O_W0L 0
#define O_W0S 65536
#define O_W0H 327680
#define O_W1L 589824
#define O_W1S 622592
#define O_W1H 655360
#define WPK_HALVES 688128

// ---------------------------------------------------------------------------
// Pack the 6 weight matrices to fp16 hi/lo in MFMA B-fragment k-major layout.
// ---------------------------------------------------------------------------
__global__ __launch_bounds__(256) void pack_w_kernel(
    const float* __restrict__ W0l, const float* __restrict__ W0s_,
    const float* __restrict__ W0h, const float* __restrict__ W1l,
    const float* __restrict__ W1s_, const float* __restrict__ W1h,
    _Float16* __restrict__ pk)
{
    const int id = blockIdx.y;
    const float* src; int K, N, offhi;
    switch (id) {
        case 0:  src = W0l;  K = 128; N = 256; offhi = O_W0L; break;
        case 1:  src = W0s_; K = 512; N = 256; offhi = O_W0S; break;
        case 2:  src = W0h;  K = 512; N = 256; offhi = O_W0H; break;
        case 3:  src = W1l;  K = 256; N = 64;  offhi = O_W1L; break;
        case 4:  src = W1s_; K = 256; N = 64;  offhi = O_W1S; break;
        default: src = W1h;  K = 256; N = 64;  offhi = O_W1H; break;
    }
    const int cnt = (K * N) >> 3;
    const int idx = blockIdx.x * 256 + threadIdx.x;
    if (idx >= cnt) return;
    const int col  = (N == 256) ? (idx & 255) : (idx & 63);
    const int kblk = (N == 256) ? (idx >> 8) : (idx >> 6);
    h8v hi, lo;
    #pragma unroll
    for (int e = 0; e < 8; ++e) {
        float x = src[(size_t)(kblk * 8 + e) * N + col];
        _Float16 h = (_Float16)x;
        hi[e] = h;
        lo[e] = (_Float16)(x - (float)h);
    }
    *reinterpret_cast<h8v*>(&pk[(size_t)offhi + (size_t)idx * 8]) = hi;
    *reinterpret_cast<h8v*>(&pk[(size_t)offhi + (size_t)(K * N) + (size_t)idx * 8]) = lo;
}

// ---------------------------------------------------------------------------
// MFMA MLP (proven round 8): all three branches; br2 -> emb, ut.
// ---------------------------------------------------------------------------
__global__ __launch_bounds__(256) void mlp2_kernel(
    const float* __restrict__ ori, const float* __restrict__ sm,
    const _Float16* __restrict__ pk,
    const float* __restrict__ b0l, const float* __restrict__ b0s,
    const float* __restrict__ b0h, const float* __restrict__ b1l,
    const float* __restrict__ b1s, const float* __restrict__ b1h,
    const float* __restrict__ am_p, const float* __restrict__ ah_p,
    float* __restrict__ out, float* __restrict__ emb, float* __restrict__ ut)
{
    __shared__ __align__(16) char smem[64 * 264 * 4];
    float* xs   = (float*)smem;
    float* hs   = (float*)smem;
    float* vals = (float*)smem;

    const int t = threadIdx.x;
    const int br = blockIdx.y;
    const int r0 = blockIdx.x * 64;
    const int w = t >> 6, lane = t & 63, arow = lane & 15, ag = lane >> 4;

    const float* X;
    const _Float16 *B0hi, *B0lo, *B1hi, *B1lo;
    const float *bias0, *bias1;
    int K1; float alpha;
    if (br == 0) {
        X = ori; B0hi = pk + O_W0L; B0lo = B0hi + 128 * 256;
        B1hi = pk + O_W1L; B1lo = B1hi + 256 * 64;
        bias0 = b0l; bias1 = b1l; K1 = FEATN; alpha = am_p[0];
    } else if (br == 1) {
        X = sm; B0hi = pk + O_W0S; B0lo = B0hi + 512 * 256;
        B1hi = pk + O_W1S; B1lo = B1hi + 256 * 64;
        bias0 = b0s; bias1 = b1s; K1 = INSM; alpha = am_p[0];
    } else {
        X = sm; B0hi = pk + O_W0H; B0lo = B0hi + 512 * 256;
        B1hi = pk + O_W1H; B1lo = B1hi + 256 * 64;
        bias0 = b0h; bias1 = b1h; K1 = INSM; alpha = ah_p[0];
    }
    const int nks = K1 >> 5;

    const int srow = t >> 2, sseg = t & 3;
    const float* Xrow = X + (size_t)(r0 + srow) * K1 + sseg * 8;

    {
        float4 a = *reinterpret_cast<const float4*>(Xrow);
        float4 b = *reinterpret_cast<const float4*>(Xrow + 4);
        float* p = &xs[(0 * 64 + srow) * 32 + sseg * 8];
        *reinterpret_cast<float4*>(p) = a;
        *reinterpret_cast<float4*>(p + 4) = b;
    }
    __syncthreads();

    f32x4 acc1[4][4] = {};
    for (int ks = 0; ks < nks; ++ks) {
        const int buf = ks & 1;
        if (ks + 1 < nks) {
            const float* g = Xrow + (ks + 1) * 32;
            float4 a = *reinterpret_cast<const float4*>(g);
            float4 b = *reinterpret_cast<const float4*>(g + 4);
            float* p = &xs[((buf ^ 1) * 64 + srow) * 32 + sseg * 8];
            *reinterpret_cast<float4*>(p) = a;
            *reinterpret_cast<float4*>(p + 4) = b;
        }
        h8v ahi[4], alo[4];
        #pragma unroll
        for (int rt = 0; rt < 4; ++rt) {
            const float* ap = &xs[(buf * 64 + rt * 16 + arow) * 32 + ag * 8];
            float4 a = *reinterpret_cast<const float4*>(ap);
            float4 b = *reinterpret_cast<const float4*>(ap + 4);
            float fv[8] = {a.x, a.y, a.z, a.w, b.x, b.y, b.z, b.w};
            #pragma unroll
            for (int e = 0; e < 8; ++e) {
                _Float16 h = (_Float16)fv[e];
                ahi[rt][e] = h;
                alo[rt][e] = (_Float16)(fv[e] - (float)h);
            }
        }
        #pragma unroll
        for (int ct = 0; ct < 4; ++ct) {
            const size_t bidx =
                ((size_t)(ks * 4 + ag) * 256 + w * 64 + ct * 16 + arow) * 8;
            h8v bhi = *reinterpret_cast<const h8v*>(&B0hi[bidx]);
            h8v blo = *reinterpret_cast<const h8v*>(&B0lo[bidx]);
            #pragma unroll
            for (int rt = 0; rt < 4; ++rt) {
                acc1[rt][ct] = __builtin_amdgcn_mfma_f32_16x16x32_f16(ahi[rt], bhi, acc1[rt][ct], 0, 0, 0);
                acc1[rt][ct] = __builtin_amdgcn_mfma_f32_16x16x32_f16(ahi[rt], blo, acc1[rt][ct], 0, 0, 0);
                acc1[rt][ct] = __builtin_amdgcn_mfma_f32_16x16x32_f16(alo[rt], bhi, acc1[rt][ct], 0, 0, 0);
            }
        }
        __syncthreads();
    }

    #pragma unroll
    for (int ct = 0; ct < 4; ++ct) {
        const int col = w * 64 + ct * 16 + arow;
        const float bb = bias0[col];
        #pragma unroll
        for (int rt = 0; rt < 4; ++rt)
            #pragma unroll
            for (int r = 0; r < 4; ++r) {
                float h = acc1[rt][ct][r] + bb;
                hs[(rt * 16 + ag * 4 + r) * 264 + col] = (h >= 0.f) ? h : alpha * h;
            }
    }
    __syncthreads();

    f32x4 acc2[4] = {};
    #pragma unroll
    for (int ks2 = 0; ks2 < 8; ++ks2) {
        const size_t bidx = ((size_t)(ks2 * 4 + ag) * 64 + w * 16 + arow) * 8;
        h8v bhi = *reinterpret_cast<const h8v*>(&B1hi[bidx]);
        h8v blo = *reinterpret_cast<const h8v*>(&B1lo[bidx]);
        #pragma unroll
        for (int rt = 0; rt < 4; ++rt) {
            const float* ap = &hs[(rt * 16 + arow) * 264 + ks2 * 32 + ag * 8];
            float4 a = *reinterpret_cast<const float4*>(ap);
            float4 b = *reinterpret_cast<const float4*>(ap + 4);
            float fv[8] = {a.x, a.y, a.z, a.w, b.x, b.y, b.z, b.w};
            h8v ahi8, alo8;
            #pragma unroll
            for (int e = 0; e < 8; ++e) {
                _Float16 h = (_Float16)fv[e];
                ahi8[e] = h;
                alo8[e] = (_Float16)(fv[e] - (float)h);
            }
            acc2[rt] = __builtin_amdgcn_mfma_f32_16x16x32_f16(ahi8, bhi, acc2[rt], 0, 0, 0);
            acc2[rt] = __builtin_amdgcn_mfma_f32_16x16x32_f16(ahi8, blo, acc2[rt], 0, 0, 0);
            acc2[rt] = __builtin_amdgcn_mfma_f32_16x16x32_f16(alo8, bhi, acc2[rt], 0, 0, 0);
        }
    }

    const int col2 = w * 16 + arow;
    const float bb1 = bias1[col2];
    if (br < 2) {
        float* dst = out + (size_t)br * NN * DOUT;
        #pragma unroll
        for (int rt = 0; rt < 4; ++rt)
            #pragma unroll
            for (int r = 0; r < 4; ++r)
                dst[(size_t)(r0 + rt * 16 + ag * 4 + r) * 64 + col2] =
                    acc2[rt][r] + bb1;
    } else {
        __syncthreads();
        #pragma unroll
        for (int rt = 0; rt < 4; ++rt)
            #pragma unroll
            for (int r = 0; r < 4; ++r)
                vals[(rt * 16 + ag * 4 + r) * 65 + col2] = acc2[rt][r] + bb1;
        __syncthreads();
        for (int rr = 0; rr < 16; ++rr) {
            const int row = w * 16 + rr;
            float v = vals[row * 65 + lane];
            float mv = v;
            for (int off = 32; off > 0; off >>= 1) mv = fmaxf(mv, __shfl_xor(mv, off));
            float e = expf(v - mv);
            float ssum = e;
            for (int off = 32; off > 0; off >>= 1) ssum += __shfl_xor(ssum, off);
            float s = e / ssum;
            float n2 = s * s;
            for (int off = 32; off > 0; off >>= 1) n2 += __shfl_xor(n2, off);
            float uu = s * rsqrtf(n2);
            emb[(size_t)(r0 + row) * 64 + lane] = v;
            ut[(size_t)lane * NN + (r0 + row)] = uu;
        }
    }
}

// ---------------------------------------------------------------------------
// Column sums of u (= row sums of ut) in f64.
// ---------------------------------------------------------------------------
__global__ __launch_bounds__(256) void colsum_kernel(const float* __restrict__ ut,
                                                     double* __restrict__ colsum)
{
    __shared__ double cred[4];
    const int c = blockIdx.x, t = threadIdx.x;
    double a = 0.0;
    for (int i = t; i < NN; i += 256) a += (double)ut[(size_t)c * NN + i];
    for (int off = 32; off > 0; off >>= 1) a += __shfl_xor(a, off);
    if ((t & 63) == 0) cred[t >> 6] = a;
    __syncthreads();
    if (t == 0) colsum[c] = cred[0] + cred[1] + cred[2] + cred[3];
}

// ---------------------------------------------------------------------------
// emb -> fp16 hi/lo, k-major packed for MFMA B-fragments.
// ---------------------------------------------------------------------------
__global__ __launch_bounds__(256) void emb_split_kernel(
    const float* __restrict__ emb, _Float16* __restrict__ ehi,
    _Float16* __restrict__ elo)
{
    const int idx = blockIdx.x * 256 + threadIdx.x;
    const int c = idx & 63, jblk = idx >> 6;
    h8v hi, lo;
    #pragma unroll
    for (int e = 0; e < 8; ++e) {
        float x = emb[(size_t)(jblk * 8 + e) * 64 + c];
        _Float16 h = (_Float16)x;
        hi[e] = h;
        lo[e] = (_Float16)(x - (float)h);
    }
    *reinterpret_cast<h8v*>(&ehi[(size_t)idx * 8]) = hi;
    *reinterpret_cast<h8v*>(&elo[(size_t)idx * 8]) = lo;
}

// ---------------------------------------------------------------------------
// ut -> fp16 hi/lo, packed as MFMA B-fragments for R = u u^T.
// ---------------------------------------------------------------------------
__global__ __launch_bounds__(256) void ut_split_kernel(
    const float* __restrict__ ut, _Float16* __restrict__ phi,
    _Float16* __restrict__ plo)
{
    const int j = blockIdx.x * 256 + threadIdx.x;
    const int kblk = blockIdx.y;
    h8v hi, lo;
    #pragma unroll
    for (int e = 0; e < 8; ++e) {
        float x = ut[(size_t)(kblk * 8 + e) * NN + j];
        _Float16 h = (_Float16)x;
        hi[e] = h;
        lo[e] = (_Float16)(x - (float)h);
    }
    const size_t o = ((size_t)kblk * NN + j) * 8;
    *reinterpret_cast<h8v*>(&phi[o]) = hi;
    *reinterpret_cast<h8v*>(&plo[o]) = lo;
}

// ---------------------------------------------------------------------------
// MFMA max pass (proven round 9): max_{i!=j} R_ij, upper-triangle tiles.
// ---------------------------------------------------------------------------
__global__ __launch_bounds__(256) void max4_kernel(
    const float* __restrict__ ut, const _Float16* __restrict__ uphi,
    const _Float16* __restrict__ uplo, unsigned int* __restrict__ mx)
{
    const int ti = blockIdx.x, tj = blockIdx.y;
    if (tj < ti) return;
    __shared__ float uis[64 * 68];
    __shared__ float red[4];
    const int t = threadIdx.x;
    {
        const int r = t & 63, kb = t >> 6;
        #pragma unroll
        for (int kk = 0; kk < 4; ++kk) {
            const int k0 = (kb + kk * 4) * 4;
            float4 v;
            v.x = ut[(size_t)(k0 + 0) * NN + ti * 64 + r];
            v.y = ut[(size_t)(k0 + 1) * NN + ti * 64 + r];
            v.z = ut[(size_t)(k0 + 2) * NN + ti * 64 + r];
            v.w = ut[(size_t)(k0 + 3) * NN + ti * 64 + r];
            *reinterpret_cast<float4*>(&uis[r * 68 + k0]) = v;
        }
    }
    __syncthreads();
    const int w = t >> 6, l = t & 63, arow = l & 15, ag = l >> 4;
    h8v ahi[4][2], alo[4][2];
    #pragma unroll
    for (int rt = 0; rt < 4; ++rt)
        #pragma unroll
        for (int ks = 0; ks < 2; ++ks) {
            const float* ap = &uis[(rt * 16 + arow) * 68 + ks * 32 + ag * 8];
            float4 a = *reinterpret_cast<const float4*>(ap);
            float4 b = *reinterpret_cast<const float4*>(ap + 4);
            float fv[8] = {a.x, a.y, a.z, a.w, b.x, b.y, b.z, b.w};
            #pragma unroll
            for (int e = 0; e < 8; ++e) {
                _Float16 h = (_Float16)fv[e];
                ahi[rt][ks][e] = h;
                alo[rt][ks][e] = (_Float16)(fv[e] - (float)h);
            }
        }
    f32x4 acc[4] = {};
    #pragma unroll
    for (int ks = 0; ks < 2; ++ks) {
        const size_t bidx = ((size_t)(ks * 4 + ag) * NN + tj * 64 + w * 16 + arow) * 8;
        h8v bhi = *reinterpret_cast<const h8v*>(&uphi[bidx]);
        h8v blo = *reinterpret_cast<const h8v*>(&uplo[bidx]);
        #pragma unroll
        for (int rt = 0; rt < 4; ++rt) {
            acc[rt] = __builtin_amdgcn_mfma_f32_16x16x32_f16(ahi[rt][ks], bhi, acc[rt], 0, 0, 0);
            acc[rt] = __builtin_amdgcn_mfma_f32_16x16x32_f16(ahi[rt][ks], blo, acc[rt], 0, 0, 0);
            acc[rt] = __builtin_amdgcn_mfma_f32_16x16x32_f16(alo[rt][ks], bhi, acc[rt], 0, 0, 0);
        }
    }
    float lm = 0.f;
    const int gj = tj * 64 + w * 16 + arow;
    #pragma unroll
    for (int rt = 0; rt < 4; ++rt)
        #pragma unroll
        for (int r = 0; r < 4; ++r) {
            const int gi = ti * 64 + rt * 16 + ag * 4 + r;
            if (gi != gj) lm = fmaxf(lm, acc[rt][r]);
        }
    for (int off = 32; off > 0; off >>= 1) lm = fmaxf(lm, __shfl_xor(lm, off));
    if ((t & 63) == 0) red[t >> 6] = lm;
    __syncthreads();
    if (t == 0) {
        float bm = fmaxf(fmaxf(red[0], red[1]), fmaxf(red[2], red[3]));
        atomicMax(mx, __float_as_uint(bm));
    }
}

__global__ void finalize_kernel(const double* __restrict__ colsum,
                                const unsigned int* __restrict__ mx,
                                float* __restrict__ scal)
{
    const int c = threadIdx.x;
    double cs = colsum[c];
    double s2 = cs * cs;
    for (int off = 32; off > 0; off >>= 1) s2 += __shfl_xor(s2, off);
    if (c == 0) {
        double md = (s2 - (double)NN) / ((double)NN * (double)NN);
        float mf = (float)md;
        float mxv = __uint_as_float(mx[0]);
        scal[0] = mf;
        scal[1] = 1.0f / (mxv - mf);
        scal[2] = 1.0f / mf;
    }
}

// ---------------------------------------------------------------------------
// Fused propagation, j-split x4 for occupancy: grid (384, 4) = 1536 blocks
// (6 blocks/CU, 24 waves/CU). Block (bi, q) computes rows bi*16..+15 over
// j-tiles [q*24, q*24+24), accumulating P/L logit partials -> ws.
// Producer/consumer structure identical to round-9 prop4 (proven math).
// ---------------------------------------------------------------------------
__global__ __launch_bounds__(256) void prop4b_kernel(
    const float* __restrict__ ut,
    const _Float16* __restrict__ uphi, const _Float16* __restrict__ uplo,
    const _Float16* __restrict__ ehi, const _Float16* __restrict__ elo,
    const float* __restrict__ scal, const float* __restrict__ ah_p,
    float* __restrict__ part)
{
    __shared__ float uis[16 * 68];
    __shared__ __align__(16) _Float16 Abuf[2][4][1024];

    const int t = threadIdx.x;
    const int bi = blockIdx.x;
    const int q = blockIdx.y;
    const int gi0 = bi * 16;
    const float m = scal[0], inv_pd = scal[1], inv_m = scal[2];
    const float alpha = ah_p[0];

    {   // stage uis[r][k] = ut[k][gi0+r]
        const int r = t & 15, kb = t >> 4;
        const int k0 = kb * 4;
        float4 v;
        v.x = ut[(size_t)(k0 + 0) * NN + gi0 + r];
        v.y = ut[(size_t)(k0 + 1) * NN + gi0 + r];
        v.z = ut[(size_t)(k0 + 2) * NN + gi0 + r];
        v.w = ut[(size_t)(k0 + 3) * NN + gi0 + r];
        *reinterpret_cast<float4*>(&uis[r * 68 + k0]) = v;
    }
    __syncthreads();

    const int w = t >> 6, l = t & 63, arow = l & 15, ag = l >> 4;
    const int col = w * 16 + arow;
    const int gl = col >> 3;
    const int b0 = (col & 7) << 1;

    h8v uahi[2], ualo[2];
    #pragma unroll
    for (int ks = 0; ks < 2; ++ks) {
        const float* ap = &uis[arow * 68 + ks * 32 + ag * 8];
        float4 a = *reinterpret_cast<const float4*>(ap);
        float4 b = *reinterpret_cast<const float4*>(ap + 4);
        float fv[8] = {a.x, a.y, a.z, a.w, b.x, b.y, b.z, b.w};
        #pragma unroll
        for (int e = 0; e < 8; ++e) {
            _Float16 h = (_Float16)fv[e];
            uahi[ks][e] = h;
            ualo[ks][e] = (_Float16)(fv[e] - (float)h);
        }
    }

    f32x4 accP = {0.f, 0.f, 0.f, 0.f};
    f32x4 accL = {0.f, 0.f, 0.f, 0.f};

    const int jt0 = q * 24, jt1 = jt0 + 24;
    for (int jt = jt0; jt < jt1; ++jt) {
        const int buf = jt & 1;
        // ---- producer: R-frag via MFMA (2 independent chains), transform ----
        {
            f32x4 accRa = {0.f, 0.f, 0.f, 0.f};
            f32x4 accRb = {0.f, 0.f, 0.f, 0.f};
            {
                const size_t bidx = ((size_t)(0 * 4 + ag) * NN + jt * 64 + col) * 8;
                h8v bhi = *reinterpret_cast<const h8v*>(&uphi[bidx]);
                h8v blo = *reinterpret_cast<const h8v*>(&uplo[bidx]);
                accRa = __builtin_amdgcn_mfma_f32_16x16x32_f16(uahi[0], bhi, accRa, 0, 0, 0);
                accRa = __builtin_amdgcn_mfma_f32_16x16x32_f16(uahi[0], blo, accRa, 0, 0, 0);
                accRa = __builtin_amdgcn_mfma_f32_16x16x32_f16(ualo[0], bhi, accRa, 0, 0, 0);
            }
            {
                const size_t bidx = ((size_t)(1 * 4 + ag) * NN + jt * 64 + col) * 8;
                h8v bhi = *reinterpret_cast<const h8v*>(&uphi[bidx]);
                h8v blo = *reinterpret_cast<const h8v*>(&uplo[bidx]);
                accRb = __builtin_amdgcn_mfma_f32_16x16x32_f16(uahi[1], bhi, accRb, 0, 0, 0);
                accRb = __builtin_amdgcn_mfma_f32_16x16x32_f16(uahi[1], blo, accRb, 0, 0, 0);
                accRb = __builtin_amdgcn_mfma_f32_16x16x32_f16(ualo[1], bhi, accRb, 0, 0, 0);
            }
            const int gjj = jt * 64 + col;
            char* base = (char*)&Abuf[buf][0][0];
            #pragma unroll
            for (int r = 0; r < 4; ++r) {
                const int row = ag * 4 + r;
                const int gi = gi0 + row;
                float rv = accRa[r] + accRb[r];
                float lre = (gi == gjj) ? 0.f : rv;
                float x = lre - m;
                float v = (x > 0.f) ? x * inv_pd : -(lre * inv_m);
                if (gi == gjj) v += 1.f;                 // add_diag after where
                float p = (v >= 0.f) ? v : alpha * v;
                _Float16 vh = (_Float16)v;
                _Float16 ph = (_Float16)p;
                _Float16 vl = (_Float16)(v - (float)vh);
                _Float16 pl = (_Float16)(p - (float)ph);
                const int byte = row * 128 + ((gl ^ (row & 7)) << 4) + b0;
                *reinterpret_cast<_Float16*>(base + byte) = vh;
                *reinterpret_cast<_Float16*>(base + 2048 + byte) = vl;
                *reinterpret_cast<_Float16*>(base + 4096 + byte) = ph;
                *reinterpret_cast<_Float16*>(base + 6144 + byte) = pl;
            }
        }
        __syncthreads();

        // ---- consumer: P/L logit MFMAs ----
        const char* cbase = (const char*)&Abuf[buf][0][0];
        #pragma unroll
        for (int ks = 0; ks < 2; ++ks) {
            const int abyte = arow * 128 + (((ks * 4 + ag) ^ (arow & 7)) << 4);
            h8v vhiF = *reinterpret_cast<const h8v*>(cbase + abyte);
            h8v vloF = *reinterpret_cast<const h8v*>(cbase + 2048 + abyte);
            h8v phiF = *reinterpret_cast<const h8v*>(cbase + 4096 + abyte);
            h8v ploF = *reinterpret_cast<const h8v*>(cbase + 6144 + abyte);
            const size_t bidx = ((size_t)(jt * 8 + ks * 4 + ag) * 64 + col) * 8;
            h8v Bhi = *reinterpret_cast<const h8v*>(&ehi[bidx]);
            h8v Blo = *reinterpret_cast<const h8v*>(&elo[bidx]);
            accP = __builtin_amdgcn_mfma_f32_16x16x32_f16(phiF, Bhi, accP, 0, 0, 0);
            accP = __builtin_amdgcn_mfma_f32_16x16x32_f16(phiF, Blo, accP, 0, 0, 0);
            accP = __builtin_amdgcn_mfma_f32_16x16x32_f16(ploF, Bhi, accP, 0, 0, 0);
            accL = __builtin_amdgcn_mfma_f32_16x16x32_f16(vhiF, Bhi, accL, 0, 0, 0);
            accL = __builtin_amdgcn_mfma_f32_16x16x32_f16(vhiF, Blo, accL, 0, 0, 0);
            accL = __builtin_amdgcn_mfma_f32_16x16x32_f16(vloF, Bhi, accL, 0, 0, 0);
        }
        __syncthreads();
    }

    // ---- write P/L partials for this quarter ----
    {
        float* pbase = &part[((size_t)q * NN + gi0) * 128];
        #pragma unroll
        for (int r = 0; r < 4; ++r) {
            const int row = ag * 4 + r;
            pbase[(size_t)row * 128 + col] = accP[r];
            pbase[(size_t)row * 128 + 64 + col] = accL[r];
        }
    }
}

// ---------------------------------------------------------------------------
// Combine quarters: P = sum, L = sum, N = P - (1+alpha)L, dual softmax,
// epilogue -> out3. 384 blocks x 16 rows (4 rows/wave).
// ---------------------------------------------------------------------------
__global__ __launch_bounds__(256) void combine4_kernel(
    const float* __restrict__ part, const float* __restrict__ emb,
    const float* __restrict__ ah_p, float* __restrict__ out3)
{
    const int t = threadIdx.x;
    const int w = t >> 6, l = t & 63;
    const int gi0 = blockIdx.x * 16;
    const float one_pa = 1.f + ah_p[0];
    #pragma unroll
    for (int rr = 0; rr < 4; ++rr) {
        const int gi = gi0 + w * 4 + rr;
        float zp = 0.f, zl = 0.f;
        #pragma unroll
        for (int q = 0; q < 4; ++q) {
            const float* p = &part[((size_t)q * NN + gi) * 128];
            zp += p[l];
            zl += p[64 + l];
        }
        float zn = zp - one_pa * zl;

        float mp = zp;
        for (int off = 32; off > 0; off >>= 1) mp = fmaxf(mp, __shfl_xor(mp, off));
        float ep = __expf(zp - mp);
        float sump = ep;
        for (int off = 32; off > 0; off >>= 1) sump += __shfl_xor(sump, off);
        float pp = ep / sump;

        float mn = zn;
        for (int off = 32; off > 0; off >>= 1) mn = fmaxf(mn, __shfl_xor(mn, off));
        float en = __expf(zn - mn);
        float sumn = en;
        for (int off = 32; off > 0; off >>= 1) sumn += __shfl_xor(sumn, off);
        float pn = en / sumn;

        out3[(size_t)gi * 64 + l] = 0.5f * (pp - pn + emb[(size_t)gi * 64 + l]);
    }
}

extern "C" void kernel_launch(void* const* d_in, const int* in_sizes, int n_in,
                              void* d_out, int out_size, void* d_ws, size_t ws_size,
                              hipStream_t stream)
{
    (void)in_sizes; (void)n_in; (void)out_size; (void)ws_size;
    const float* ori = (const float*)d_in[0];
    const float* sm  = (const float*)d_in[1];
    // d_in[2] processed_feature: unused; d_in[3] universal_re: unused (BETA=0)
    const float* W0s = (const float*)d_in[4];
    const float* b0s = (const float*)d_in[5];
    const float* W1s = (const float*)d_in[6];
    const float* b1s = (const float*)d_in[7];
    const float* W0l = (const float*)d_in[8];
    const float* b0l = (const float*)d_in[9];
    const float* W1l = (const float*)d_in[10];
    const float* b1l = (const float*)d_in[11];
    const float* W0h = (const float*)d_in[12];
    const float* b0h = (const float*)d_in[13];
    const float* W1h = (const float*)d_in[14];
    const float* b1h = (const float*)d_in[15];
    const float* amp = (const float*)d_in[16];
    const float* ahp = (const float*)d_in[17];

    float* out = (float*)d_out;                       // f32 output (ref dtype)
    float* ws = (float*)d_ws;
    float* emb = ws;                                  // NN*64 f32
    float* ut  = ws + (size_t)NN * DOUT;              // 64*NN f32 (u transposed)
    double* colsum = (double*)(ws + (size_t)2 * NN * DOUT);   // 64 f64
    unsigned int* mx = (unsigned int*)(ws + (size_t)2 * NN * DOUT + 128);
    float* scal = ws + (size_t)2 * NN * DOUT + 128 + 4;       // 3 f32
    size_t eh_off = (((size_t)2 * NN * DOUT + 128 + 8) + 15) & ~(size_t)15;
    _Float16* ehi = (_Float16*)(ws + eh_off);                 // NN*64 halves
    _Float16* elo = ehi + (size_t)NN * DOUT;
    size_t up_off = eh_off + (size_t)NN * DOUT;               // f32 words
    _Float16* uphi = (_Float16*)(ws + up_off);                // NN*64 halves
    _Float16* uplo = uphi + (size_t)NN * DOUT;
    size_t wpk_off = up_off + (size_t)NN * DOUT;
    _Float16* wpk = (_Float16*)(ws + wpk_off);                // 688128 halves
    size_t part_off = (wpk_off + WPK_HALVES / 2 + 15) & ~(size_t)15;
    float* part = ws + part_off;                              // 4*NN*128 f32
    // total ws footprint ~20.3 MB (ws proven >= 155 MB by round-5 path)

    hipMemsetAsync(mx, 0, 4, stream);
    pack_w_kernel<<<dim3(64, 6), 256, 0, stream>>>(W0l, W0s, W0h, W1l, W1s, W1h, wpk);
    mlp2_kernel<<<dim3(NN / 64, 3), 256, 0, stream>>>(
        ori, sm, wpk, b0l, b0s, b0h, b1l, b1s, b1h, amp, ahp, out, emb, ut);
    colsum_kernel<<<64, 256, 0, stream>>>(ut, colsum);
    emb_split_kernel<<<NN * DOUT / 8 / 256, 256, 0, stream>>>(emb, ehi, elo);
    ut_split_kernel<<<dim3(NN / 256, 8), 256, 0, stream>>>(ut, uphi, uplo);
    max4_kernel<<<dim3(96, 96), 256, 0, stream>>>(ut, uphi, uplo, mx);
    finalize_kernel<<<1, 64, 0, stream>>>(colsum, mx, scal);
    prop4b_kernel<<<dim3(NN / 16, 4), 256, 0, stream>>>(
        ut, uphi, uplo, ehi, elo, scal, ahp, part);
    combine4_kernel<<<NN / 16, 256, 0, stream>>>(
        part, emb, ahp, out + (size_t)2 * NN * DOUT);
}

// Round 11
// 194.799 us; speedup vs baseline: 1.3339x; 1.0694x over previous
//
#include <hip/hip_runtime.h>
#include <hip/hip_bf16.h>

#define NN 6144
#define FEATN 128
#define INSM 512
#define HIDN 256
#define DOUT 64

typedef _Float16 h4v __attribute__((ext_vector_type(4)));
typedef _Float16 h8v __attribute__((ext_vector_type(8)));
typedef float f32x4 __attribute__((ext_vector_type(4)));

// Weight-pack offsets (in halves) inside the contiguous wpk buffer.
#define O_W0L 0
#define O_W0S 65536
#define O_W0H 327680
#define O_W1L 589824
#define O_W1S 622592
#define O_W1H 655360
#define WPK_HALVES 688128

// ---------------------------------------------------------------------------
// Pack the 6 weight matrices to fp16 hi/lo in MFMA B-fragment k-major layout.
// ---------------------------------------------------------------------------
__global__ __launch_bounds__(256) void pack_w_kernel(
    const float* __restrict__ W0l, const float* __restrict__ W0s_,
    const float* __restrict__ W0h, const float* __restrict__ W1l,
    const float* __restrict__ W1s_, const float* __restrict__ W1h,
    _Float16* __restrict__ pk)
{
    const int id = blockIdx.y;
    const float* src; int K, N, offhi;
    switch (id) {
        case 0:  src = W0l;  K = 128; N = 256; offhi = O_W0L; break;
        case 1:  src = W0s_; K = 512; N = 256; offhi = O_W0S; break;
        case 2:  src = W0h;  K = 512; N = 256; offhi = O_W0H; break;
        case 3:  src = W1l;  K = 256; N = 64;  offhi = O_W1L; break;
        case 4:  src = W1s_; K = 256; N = 64;  offhi = O_W1S; break;
        default: src = W1h;  K = 256; N = 64;  offhi = O_W1H; break;
    }
    const int cnt = (K * N) >> 3;
    const int idx = blockIdx.x * 256 + threadIdx.x;
    if (idx >= cnt) return;
    const int col  = (N == 256) ? (idx & 255) : (idx & 63);
    const int kblk = (N == 256) ? (idx >> 8) : (idx >> 6);
    h8v hi, lo;
    #pragma unroll
    for (int e = 0; e < 8; ++e) {
        float x = src[(size_t)(kblk * 8 + e) * N + col];
        _Float16 h = (_Float16)x;
        hi[e] = h;
        lo[e] = (_Float16)(x - (float)h);
    }
    *reinterpret_cast<h8v*>(&pk[(size_t)offhi + (size_t)idx * 8]) = hi;
    *reinterpret_cast<h8v*>(&pk[(size_t)offhi + (size_t)(K * N) + (size_t)idx * 8]) = lo;
}

// ---------------------------------------------------------------------------
// MFMA MLP, 32-row tiles for occupancy: grid (192, 3), LDS 34 KB -> 4 blk/CU.
// Same math as the proven 64-row version (per-element accumulation order
// unchanged). br==2 epilogue: row softmax + L2 normalize -> emb, ut.
// ---------------------------------------------------------------------------
__global__ __launch_bounds__(256) void mlp2_kernel(
    const float* __restrict__ ori, const float* __restrict__ sm,
    const _Float16* __restrict__ pk,
    const float* __restrict__ b0l, const float* __restrict__ b0s,
    const float* __restrict__ b0h, const float* __restrict__ b1l,
    const float* __restrict__ b1s, const float* __restrict__ b1h,
    const float* __restrict__ am_p, const float* __restrict__ ah_p,
    float* __restrict__ out, float* __restrict__ emb, float* __restrict__ ut)
{
    __shared__ __align__(16) char smem[32 * 264 * 4];   // 33792 B
    float* xs   = (float*)smem;     // [2][32][32] dbuf, 8 KB (layer1 phase)
    float* hs   = (float*)smem;     // [32][264] f32 (layer2 phase)
    float* vals = (float*)smem;     // [32][65] f32 (br2 softmax phase)

    const int t = threadIdx.x;
    const int br = blockIdx.y;
    const int r0 = blockIdx.x * 32;
    const int w = t >> 6, lane = t & 63, arow = lane & 15, ag = lane >> 4;

    const float* X;
    const _Float16 *B0hi, *B0lo, *B1hi, *B1lo;
    const float *bias0, *bias1;
    int K1; float alpha;
    if (br == 0) {
        X = ori; B0hi = pk + O_W0L; B0lo = B0hi + 128 * 256;
        B1hi = pk + O_W1L; B1lo = B1hi + 256 * 64;
        bias0 = b0l; bias1 = b1l; K1 = FEATN; alpha = am_p[0];
    } else if (br == 1) {
        X = sm; B0hi = pk + O_W0S; B0lo = B0hi + 512 * 256;
        B1hi = pk + O_W1S; B1lo = B1hi + 256 * 64;
        bias0 = b0s; bias1 = b1s; K1 = INSM; alpha = am_p[0];
    } else {
        X = sm; B0hi = pk + O_W0H; B0lo = B0hi + 512 * 256;
        B1hi = pk + O_W1H; B1lo = B1hi + 256 * 64;
        bias0 = b0h; bias1 = b1h; K1 = INSM; alpha = ah_p[0];
    }
    const int nks = K1 >> 5;

    // ---- layer 1: H[32][256] = prelu(X@W0 + b0) ----
    const int srow = t >> 3, sseg = t & 7;           // staging: 8 thr/row
    const float* Xrow = X + (size_t)(r0 + srow) * K1 + sseg * 4;

    {   // stage ks = 0
        float4 a = *reinterpret_cast<const float4*>(Xrow);
        *reinterpret_cast<float4*>(&xs[(0 * 32 + srow) * 32 + sseg * 4]) = a;
    }
    __syncthreads();

    f32x4 acc1[2][4] = {};                            // [rowtile][coltile]
    for (int ks = 0; ks < nks; ++ks) {
        const int buf = ks & 1;
        if (ks + 1 < nks) {                           // stage next slab
            float4 a = *reinterpret_cast<const float4*>(Xrow + (ks + 1) * 32);
            *reinterpret_cast<float4*>(
                &xs[((buf ^ 1) * 32 + srow) * 32 + sseg * 4]) = a;
        }
        h8v ahi[2], alo[2];
        #pragma unroll
        for (int rt = 0; rt < 2; ++rt) {              // A-frags, split hi/lo
            const float* ap = &xs[(buf * 32 + rt * 16 + arow) * 32 + ag * 8];
            float4 a = *reinterpret_cast<const float4*>(ap);
            float4 b = *reinterpret_cast<const float4*>(ap + 4);
            float fv[8] = {a.x, a.y, a.z, a.w, b.x, b.y, b.z, b.w};
            #pragma unroll
            for (int e = 0; e < 8; ++e) {
                _Float16 h = (_Float16)fv[e];
                ahi[rt][e] = h;
                alo[rt][e] = (_Float16)(fv[e] - (float)h);
            }
        }
        #pragma unroll
        for (int ct = 0; ct < 4; ++ct) {
            const size_t bidx =
                ((size_t)(ks * 4 + ag) * 256 + w * 64 + ct * 16 + arow) * 8;
            h8v bhi = *reinterpret_cast<const h8v*>(&B0hi[bidx]);
            h8v blo = *reinterpret_cast<const h8v*>(&B0lo[bidx]);
            #pragma unroll
            for (int rt = 0; rt < 2; ++rt) {
                acc1[rt][ct] = __builtin_amdgcn_mfma_f32_16x16x32_f16(ahi[rt], bhi, acc1[rt][ct], 0, 0, 0);
                acc1[rt][ct] = __builtin_amdgcn_mfma_f32_16x16x32_f16(ahi[rt], blo, acc1[rt][ct], 0, 0, 0);
                acc1[rt][ct] = __builtin_amdgcn_mfma_f32_16x16x32_f16(alo[rt], bhi, acc1[rt][ct], 0, 0, 0);
            }
        }
        __syncthreads();                              // slab reads done
    }

    // epilogue L1: bias + prelu -> hs (xs dead; hs aliases it)
    #pragma unroll
    for (int ct = 0; ct < 4; ++ct) {
        const int col = w * 64 + ct * 16 + arow;
        const float bb = bias0[col];
        #pragma unroll
        for (int rt = 0; rt < 2; ++rt)
            #pragma unroll
            for (int r = 0; r < 4; ++r) {
                float h = acc1[rt][ct][r] + bb;       // C/D row = ag*4+r
                hs[(rt * 16 + ag * 4 + r) * 264 + col] = (h >= 0.f) ? h : alpha * h;
            }
    }
    __syncthreads();

    // ---- layer 2: O[32][64] = H@W1 + b1 (K=256, 8 K-steps) ----
    f32x4 acc2[2] = {};
    #pragma unroll
    for (int ks2 = 0; ks2 < 8; ++ks2) {
        const size_t bidx = ((size_t)(ks2 * 4 + ag) * 64 + w * 16 + arow) * 8;
        h8v bhi = *reinterpret_cast<const h8v*>(&B1hi[bidx]);
        h8v blo = *reinterpret_cast<const h8v*>(&B1lo[bidx]);
        #pragma unroll
        for (int rt = 0; rt < 2; ++rt) {
            const float* ap = &hs[(rt * 16 + arow) * 264 + ks2 * 32 + ag * 8];
            float4 a = *reinterpret_cast<const float4*>(ap);
            float4 b = *reinterpret_cast<const float4*>(ap + 4);
            float fv[8] = {a.x, a.y, a.z, a.w, b.x, b.y, b.z, b.w};
            h8v ahi8, alo8;
            #pragma unroll
            for (int e = 0; e < 8; ++e) {
                _Float16 h = (_Float16)fv[e];
                ahi8[e] = h;
                alo8[e] = (_Float16)(fv[e] - (float)h);
            }
            acc2[rt] = __builtin_amdgcn_mfma_f32_16x16x32_f16(ahi8, bhi, acc2[rt], 0, 0, 0);
            acc2[rt] = __builtin_amdgcn_mfma_f32_16x16x32_f16(ahi8, blo, acc2[rt], 0, 0, 0);
            acc2[rt] = __builtin_amdgcn_mfma_f32_16x16x32_f16(alo8, bhi, acc2[rt], 0, 0, 0);
        }
    }

    const int col2 = w * 16 + arow;
    const float bb1 = bias1[col2];
    if (br < 2) {
        float* dst = out + (size_t)br * NN * DOUT;
        #pragma unroll
        for (int rt = 0; rt < 2; ++rt)
            #pragma unroll
            for (int r = 0; r < 4; ++r)
                dst[(size_t)(r0 + rt * 16 + ag * 4 + r) * 64 + col2] =
                    acc2[rt][r] + bb1;
    } else {
        __syncthreads();                              // hs reads done; vals aliases
        #pragma unroll
        for (int rt = 0; rt < 2; ++rt)
            #pragma unroll
            for (int r = 0; r < 4; ++r)
                vals[(rt * 16 + ag * 4 + r) * 65 + col2] = acc2[rt][r] + bb1;
        __syncthreads();
        // row softmax (64 lanes) + L2 normalize; wave w owns rows w*8..+7
        for (int rr = 0; rr < 8; ++rr) {
            const int row = w * 8 + rr;
            float v = vals[row * 65 + lane];
            float mv = v;
            for (int off = 32; off > 0; off >>= 1) mv = fmaxf(mv, __shfl_xor(mv, off));
            float e = expf(v - mv);
            float ssum = e;
            for (int off = 32; off > 0; off >>= 1) ssum += __shfl_xor(ssum, off);
            float s = e / ssum;
            float n2 = s * s;
            for (int off = 32; off > 0; off >>= 1) n2 += __shfl_xor(n2, off);
            float uu = s * rsqrtf(n2);    // d_i >= 1/64 so max(.,1e-9) never binds
            emb[(size_t)(r0 + row) * 64 + lane] = v;
            ut[(size_t)lane * NN + (r0 + row)] = uu;
        }
    }
}

// ---------------------------------------------------------------------------
// Column sums of u (= row sums of ut) in f64.
// ---------------------------------------------------------------------------
__global__ __launch_bounds__(256) void colsum_kernel(const float* __restrict__ ut,
                                                     double* __restrict__ colsum)
{
    __shared__ double cred[4];
    const int c = blockIdx.x, t = threadIdx.x;
    double a = 0.0;
    for (int i = t; i < NN; i += 256) a += (double)ut[(size_t)c * NN + i];
    for (int off = 32; off > 0; off >>= 1) a += __shfl_xor(a, off);
    if ((t & 63) == 0) cred[t >> 6] = a;
    __syncthreads();
    if (t == 0) colsum[c] = cred[0] + cred[1] + cred[2] + cred[3];
}

// ---------------------------------------------------------------------------
// emb -> fp16 hi/lo, k-major packed for MFMA B-fragments.
// ---------------------------------------------------------------------------
__global__ __launch_bounds__(256) void emb_split_kernel(
    const float* __restrict__ emb, _Float16* __restrict__ ehi,
    _Float16* __restrict__ elo)
{
    const int idx = blockIdx.x * 256 + threadIdx.x;
    const int c = idx & 63, jblk = idx >> 6;
    h8v hi, lo;
    #pragma unroll
    for (int e = 0; e < 8; ++e) {
        float x = emb[(size_t)(jblk * 8 + e) * 64 + c];
        _Float16 h = (_Float16)x;
        hi[e] = h;
        lo[e] = (_Float16)(x - (float)h);
    }
    *reinterpret_cast<h8v*>(&ehi[(size_t)idx * 8]) = hi;
    *reinterpret_cast<h8v*>(&elo[(size_t)idx * 8]) = lo;
}

// ---------------------------------------------------------------------------
// ut -> fp16 hi/lo, packed as MFMA B-fragments for R = u u^T.
// ---------------------------------------------------------------------------
__global__ __launch_bounds__(256) void ut_split_kernel(
    const float* __restrict__ ut, _Float16* __restrict__ phi,
    _Float16* __restrict__ plo)
{
    const int j = blockIdx.x * 256 + threadIdx.x;
    const int kblk = blockIdx.y;
    h8v hi, lo;
    #pragma unroll
    for (int e = 0; e < 8; ++e) {
        float x = ut[(size_t)(kblk * 8 + e) * NN + j];
        _Float16 h = (_Float16)x;
        hi[e] = h;
        lo[e] = (_Float16)(x - (float)h);
    }
    const size_t o = ((size_t)kblk * NN + j) * 8;
    *reinterpret_cast<h8v*>(&phi[o]) = hi;
    *reinterpret_cast<h8v*>(&plo[o]) = lo;
}

// ---------------------------------------------------------------------------
// MFMA max pass (proven round 9): max_{i!=j} R_ij, upper-triangle tiles.
// ---------------------------------------------------------------------------
__global__ __launch_bounds__(256) void max4_kernel(
    const float* __restrict__ ut, const _Float16* __restrict__ uphi,
    const _Float16* __restrict__ uplo, unsigned int* __restrict__ mx)
{
    const int ti = blockIdx.x, tj = blockIdx.y;
    if (tj < ti) return;
    __shared__ float uis[64 * 68];
    __shared__ float red[4];
    const int t = threadIdx.x;
    {
        const int r = t & 63, kb = t >> 6;
        #pragma unroll
        for (int kk = 0; kk < 4; ++kk) {
            const int k0 = (kb + kk * 4) * 4;
            float4 v;
            v.x = ut[(size_t)(k0 + 0) * NN + ti * 64 + r];
            v.y = ut[(size_t)(k0 + 1) * NN + ti * 64 + r];
            v.z = ut[(size_t)(k0 + 2) * NN + ti * 64 + r];
            v.w = ut[(size_t)(k0 + 3) * NN + ti * 64 + r];
            *reinterpret_cast<float4*>(&uis[r * 68 + k0]) = v;
        }
    }
    __syncthreads();
    const int w = t >> 6, l = t & 63, arow = l & 15, ag = l >> 4;
    h8v ahi[4][2], alo[4][2];
    #pragma unroll
    for (int rt = 0; rt < 4; ++rt)
        #pragma unroll
        for (int ks = 0; ks < 2; ++ks) {
            const float* ap = &uis[(rt * 16 + arow) * 68 + ks * 32 + ag * 8];
            float4 a = *reinterpret_cast<const float4*>(ap);
            float4 b = *reinterpret_cast<const float4*>(ap + 4);
            float fv[8] = {a.x, a.y, a.z, a.w, b.x, b.y, b.z, b.w};
            #pragma unroll
            for (int e = 0; e < 8; ++e) {
                _Float16 h = (_Float16)fv[e];
                ahi[rt][ks][e] = h;
                alo[rt][ks][e] = (_Float16)(fv[e] - (float)h);
            }
        }
    f32x4 acc[4] = {};
    #pragma unroll
    for (int ks = 0; ks < 2; ++ks) {
        const size_t bidx = ((size_t)(ks * 4 + ag) * NN + tj * 64 + w * 16 + arow) * 8;
        h8v bhi = *reinterpret_cast<const h8v*>(&uphi[bidx]);
        h8v blo = *reinterpret_cast<const h8v*>(&uplo[bidx]);
        #pragma unroll
        for (int rt = 0; rt < 4; ++rt) {
            acc[rt] = __builtin_amdgcn_mfma_f32_16x16x32_f16(ahi[rt][ks], bhi, acc[rt], 0, 0, 0);
            acc[rt] = __builtin_amdgcn_mfma_f32_16x16x32_f16(ahi[rt][ks], blo, acc[rt], 0, 0, 0);
            acc[rt] = __builtin_amdgcn_mfma_f32_16x16x32_f16(alo[rt][ks], bhi, acc[rt], 0, 0, 0);
        }
    }
    float lm = 0.f;
    const int gj = tj * 64 + w * 16 + arow;
    #pragma unroll
    for (int rt = 0; rt < 4; ++rt)
        #pragma unroll
        for (int r = 0; r < 4; ++r) {
            const int gi = ti * 64 + rt * 16 + ag * 4 + r;
            if (gi != gj) lm = fmaxf(lm, acc[rt][r]);
        }
    for (int off = 32; off > 0; off >>= 1) lm = fmaxf(lm, __shfl_xor(lm, off));
    if ((t & 63) == 0) red[t >> 6] = lm;
    __syncthreads();
    if (t == 0) {
        float bm = fmaxf(fmaxf(red[0], red[1]), fmaxf(red[2], red[3]));
        atomicMax(mx, __float_as_uint(bm));
    }
}

__global__ void finalize_kernel(const double* __restrict__ colsum,
                                const unsigned int* __restrict__ mx,
                                float* __restrict__ scal)
{
    const int c = threadIdx.x;
    double cs = colsum[c];
    double s2 = cs * cs;
    for (int off = 32; off > 0; off >>= 1) s2 += __shfl_xor(s2, off);
    if (c == 0) {
        double md = (s2 - (double)NN) / ((double)NN * (double)NN);
        float mf = (float)md;
        float mxv = __uint_as_float(mx[0]);
        scal[0] = mf;
        scal[1] = 1.0f / (mxv - mf);
        scal[2] = 1.0f / mf;
    }
}

// ---------------------------------------------------------------------------
// Fused propagation, j-split x4: grid (384, 4). One barrier per tile
// (double-buffered Abuf: P(jt+1) writes buf^1 while C(jt) reads buf; C(jt-1)
// finished before B(jt) in every wave). s_setprio(1) around the consumer
// MFMA cluster (T5; cross-block phase diversity at 6 blocks/CU).
// ---------------------------------------------------------------------------
__global__ __launch_bounds__(256) void prop4b_kernel(
    const float* __restrict__ ut,
    const _Float16* __restrict__ uphi, const _Float16* __restrict__ uplo,
    const _Float16* __restrict__ ehi, const _Float16* __restrict__ elo,
    const float* __restrict__ scal, const float* __restrict__ ah_p,
    float* __restrict__ part)
{
    __shared__ float uis[16 * 68];
    __shared__ __align__(16) _Float16 Abuf[2][4][1024];

    const int t = threadIdx.x;
    const int bi = blockIdx.x;
    const int q = blockIdx.y;
    const int gi0 = bi * 16;
    const float m = scal[0], inv_pd = scal[1], inv_m = scal[2];
    const float alpha = ah_p[0];

    {   // stage uis[r][k] = ut[k][gi0+r]
        const int r = t & 15, kb = t >> 4;
        const int k0 = kb * 4;
        float4 v;
        v.x = ut[(size_t)(k0 + 0) * NN + gi0 + r];
        v.y = ut[(size_t)(k0 + 1) * NN + gi0 + r];
        v.z = ut[(size_t)(k0 + 2) * NN + gi0 + r];
        v.w = ut[(size_t)(k0 + 3) * NN + gi0 + r];
        *reinterpret_cast<float4*>(&uis[r * 68 + k0]) = v;
    }
    __syncthreads();

    const int w = t >> 6, l = t & 63, arow = l & 15, ag = l >> 4;
    const int col = w * 16 + arow;
    const int gl = col >> 3;
    const int b0 = (col & 7) << 1;

    h8v uahi[2], ualo[2];
    #pragma unroll
    for (int ks = 0; ks < 2; ++ks) {
        const float* ap = &uis[arow * 68 + ks * 32 + ag * 8];
        float4 a = *reinterpret_cast<const float4*>(ap);
        float4 b = *reinterpret_cast<const float4*>(ap + 4);
        float fv[8] = {a.x, a.y, a.z, a.w, b.x, b.y, b.z, b.w};
        #pragma unroll
        for (int e = 0; e < 8; ++e) {
            _Float16 h = (_Float16)fv[e];
            uahi[ks][e] = h;
            ualo[ks][e] = (_Float16)(fv[e] - (float)h);
        }
    }

    f32x4 accP = {0.f, 0.f, 0.f, 0.f};
    f32x4 accL = {0.f, 0.f, 0.f, 0.f};

    const int jt0 = q * 24, jt1 = jt0 + 24;
    for (int jt = jt0; jt < jt1; ++jt) {
        const int buf = jt & 1;
        // ---- producer: R-frag via MFMA (2 independent chains), transform ----
        {
            f32x4 accRa = {0.f, 0.f, 0.f, 0.f};
            f32x4 accRb = {0.f, 0.f, 0.f, 0.f};
            {
                const size_t bidx = ((size_t)(0 * 4 + ag) * NN + jt * 64 + col) * 8;
                h8v bhi = *reinterpret_cast<const h8v*>(&uphi[bidx]);
                h8v blo = *reinterpret_cast<const h8v*>(&uplo[bidx]);
                accRa = __builtin_amdgcn_mfma_f32_16x16x32_f16(uahi[0], bhi, accRa, 0, 0, 0);
                accRa = __builtin_amdgcn_mfma_f32_16x16x32_f16(uahi[0], blo, accRa, 0, 0, 0);
                accRa = __builtin_amdgcn_mfma_f32_16x16x32_f16(ualo[0], bhi, accRa, 0, 0, 0);
            }
            {
                const size_t bidx = ((size_t)(1 * 4 + ag) * NN + jt * 64 + col) * 8;
                h8v bhi = *reinterpret_cast<const h8v*>(&uphi[bidx]);
                h8v blo = *reinterpret_cast<const h8v*>(&uplo[bidx]);
                accRb = __builtin_amdgcn_mfma_f32_16x16x32_f16(uahi[1], bhi, accRb, 0, 0, 0);
                accRb = __builtin_amdgcn_mfma_f32_16x16x32_f16(uahi[1], blo, accRb, 0, 0, 0);
                accRb = __builtin_amdgcn_mfma_f32_16x16x32_f16(ualo[1], bhi, accRb, 0, 0, 0);
            }
            const int gjj = jt * 64 + col;
            char* base = (char*)&Abuf[buf][0][0];
            #pragma unroll
            for (int r = 0; r < 4; ++r) {
                const int row = ag * 4 + r;
                const int gi = gi0 + row;
                float rv = accRa[r] + accRb[r];
                float lre = (gi == gjj) ? 0.f : rv;
                float x = lre - m;
                float v = (x > 0.f) ? x * inv_pd : -(lre * inv_m);
                if (gi == gjj) v += 1.f;                 // add_diag after where
                float p = (v >= 0.f) ? v : alpha * v;
                _Float16 vh = (_Float16)v;
                _Float16 ph = (_Float16)p;
                _Float16 vl = (_Float16)(v - (float)vh);
                _Float16 pl = (_Float16)(p - (float)ph);
                const int byte = row * 128 + ((gl ^ (row & 7)) << 4) + b0;
                *reinterpret_cast<_Float16*>(base + byte) = vh;
                *reinterpret_cast<_Float16*>(base + 2048 + byte) = vl;
                *reinterpret_cast<_Float16*>(base + 4096 + byte) = ph;
                *reinterpret_cast<_Float16*>(base + 6144 + byte) = pl;
            }
        }
        __syncthreads();        // single barrier per tile (dbuf-safe)

        // ---- consumer: P/L logit MFMAs ----
        const char* cbase = (const char*)&Abuf[buf][0][0];
        __builtin_amdgcn_s_setprio(1);
        #pragma unroll
        for (int ks = 0; ks < 2; ++ks) {
            const int abyte = arow * 128 + (((ks * 4 + ag) ^ (arow & 7)) << 4);
            h8v vhiF = *reinterpret_cast<const h8v*>(cbase + abyte);
            h8v vloF = *reinterpret_cast<const h8v*>(cbase + 2048 + abyte);
            h8v phiF = *reinterpret_cast<const h8v*>(cbase + 4096 + abyte);
            h8v ploF = *reinterpret_cast<const h8v*>(cbase + 6144 + abyte);
            const size_t bidx = ((size_t)(jt * 8 + ks * 4 + ag) * 64 + col) * 8;
            h8v Bhi = *reinterpret_cast<const h8v*>(&ehi[bidx]);
            h8v Blo = *reinterpret_cast<const h8v*>(&elo[bidx]);
            accP = __builtin_amdgcn_mfma_f32_16x16x32_f16(phiF, Bhi, accP, 0, 0, 0);
            accP = __builtin_amdgcn_mfma_f32_16x16x32_f16(phiF, Blo, accP, 0, 0, 0);
            accP = __builtin_amdgcn_mfma_f32_16x16x32_f16(ploF, Bhi, accP, 0, 0, 0);
            accL = __builtin_amdgcn_mfma_f32_16x16x32_f16(vhiF, Bhi, accL, 0, 0, 0);
            accL = __builtin_amdgcn_mfma_f32_16x16x32_f16(vhiF, Blo, accL, 0, 0, 0);
            accL = __builtin_amdgcn_mfma_f32_16x16x32_f16(vloF, Bhi, accL, 0, 0, 0);
        }
        __builtin_amdgcn_s_setprio(0);
    }

    // ---- write P/L partials for this quarter ----
    {
        float* pbase = &part[((size_t)q * NN + gi0) * 128];
        #pragma unroll
        for (int r = 0; r < 4; ++r) {
            const int row = ag * 4 + r;
            pbase[(size_t)row * 128 + col] = accP[r];
            pbase[(size_t)row * 128 + 64 + col] = accL[r];
        }
    }
}

// ---------------------------------------------------------------------------
// Combine quarters: P = sum, L = sum, N = P - (1+alpha)L, dual softmax,
// epilogue -> out3. 384 blocks x 16 rows (4 rows/wave).
// ---------------------------------------------------------------------------
__global__ __launch_bounds__(256) void combine4_kernel(
    const float* __restrict__ part, const float* __restrict__ emb,
    const float* __restrict__ ah_p, float* __restrict__ out3)
{
    const int t = threadIdx.x;
    const int w = t >> 6, l = t & 63;
    const int gi0 = blockIdx.x * 16;
    const float one_pa = 1.f + ah_p[0];
    #pragma unroll
    for (int rr = 0; rr < 4; ++rr) {
        const int gi = gi0 + w * 4 + rr;
        float zp = 0.f, zl = 0.f;
        #pragma unroll
        for (int q = 0; q < 4; ++q) {
            const float* p = &part[((size_t)q * NN + gi) * 128];
            zp += p[l];
            zl += p[64 + l];
        }
        float zn = zp - one_pa * zl;

        float mp = zp;
        for (int off = 32; off > 0; off >>= 1) mp = fmaxf(mp, __shfl_xor(mp, off));
        float ep = __expf(zp - mp);
        float sump = ep;
        for (int off = 32; off > 0; off >>= 1) sump += __shfl_xor(sump, off);
        float pp = ep / sump;

        float mn = zn;
        for (int off = 32; off > 0; off >>= 1) mn = fmaxf(mn, __shfl_xor(mn, off));
        float en = __expf(zn - mn);
        float sumn = en;
        for (int off = 32; off > 0; off >>= 1) sumn += __shfl_xor(sumn, off);
        float pn = en / sumn;

        out3[(size_t)gi * 64 + l] = 0.5f * (pp - pn + emb[(size_t)gi * 64 + l]);
    }
}

extern "C" void kernel_launch(void* const* d_in, const int* in_sizes, int n_in,
                              void* d_out, int out_size, void* d_ws, size_t ws_size,
                              hipStream_t stream)
{
    (void)in_sizes; (void)n_in; (void)out_size; (void)ws_size;
    const float* ori = (const float*)d_in[0];
    const float* sm  = (const float*)d_in[1];
    // d_in[2] processed_feature: unused; d_in[3] universal_re: unused (BETA=0)
    const float* W0s = (const float*)d_in[4];
    const float* b0s = (const float*)d_in[5];
    const float* W1s = (const float*)d_in[6];
    const float* b1s = (const float*)d_in[7];
    const float* W0l = (const float*)d_in[8];
    const float* b0l = (const float*)d_in[9];
    const float* W1l = (const float*)d_in[10];
    const float* b1l = (const float*)d_in[11];
    const float* W0h = (const float*)d_in[12];
    const float* b0h = (const float*)d_in[13];
    const float* W1h = (const float*)d_in[14];
    const float* b1h = (const float*)d_in[15];
    const float* amp = (const float*)d_in[16];
    const float* ahp = (const float*)d_in[17];

    float* out = (float*)d_out;                       // f32 output (ref dtype)
    float* ws = (float*)d_ws;
    float* emb = ws;                                  // NN*64 f32
    float* ut  = ws + (size_t)NN * DOUT;              // 64*NN f32 (u transposed)
    double* colsum = (double*)(ws + (size_t)2 * NN * DOUT);   // 64 f64
    unsigned int* mx = (unsigned int*)(ws + (size_t)2 * NN * DOUT + 128);
    float* scal = ws + (size_t)2 * NN * DOUT + 128 + 4;       // 3 f32
    size_t eh_off = (((size_t)2 * NN * DOUT + 128 + 8) + 15) & ~(size_t)15;
    _Float16* ehi = (_Float16*)(ws + eh_off);                 // NN*64 halves
    _Float16* elo = ehi + (size_t)NN * DOUT;
    size_t up_off = eh_off + (size_t)NN * DOUT;               // f32 words
    _Float16* uphi = (_Float16*)(ws + up_off);                // NN*64 halves
    _Float16* uplo = uphi + (size_t)NN * DOUT;
    size_t wpk_off = up_off + (size_t)NN * DOUT;
    _Float16* wpk = (_Float16*)(ws + wpk_off);                // 688128 halves
    size_t part_off = (wpk_off + WPK_HALVES / 2 + 15) & ~(size_t)15;
    float* part = ws + part_off;                              // 4*NN*128 f32
    // total ws footprint ~20.3 MB

    hipMemsetAsync(mx, 0, 4, stream);
    pack_w_kernel<<<dim3(64, 6), 256, 0, stream>>>(W0l, W0s, W0h, W1l, W1s, W1h, wpk);
    mlp2_kernel<<<dim3(NN / 32, 3), 256, 0, stream>>>(
        ori, sm, wpk, b0l, b0s, b0h, b1l, b1s, b1h, amp, ahp, out, emb, ut);
    colsum_kernel<<<64, 256, 0, stream>>>(ut, colsum);
    emb_split_kernel<<<NN * DOUT / 8 / 256, 256, 0, stream>>>(emb, ehi, elo);
    ut_split_kernel<<<dim3(NN / 256, 8), 256, 0, stream>>>(ut, uphi, uplo);
    max4_kernel<<<dim3(96, 96), 256, 0, stream>>>(ut, uphi, uplo, mx);
    finalize_kernel<<<1, 64, 0, stream>>>(colsum, mx, scal);
    prop4b_kernel<<<dim3(NN / 16, 4), 256, 0, stream>>>(
        ut, uphi, uplo, ehi, elo, scal, ahp, part);
    combine4_kernel<<<NN / 16, 256, 0, stream>>>(
        part, emb, ahp, out + (size_t)2 * NN * DOUT);
}

// Round 12
// 180.137 us; speedup vs baseline: 1.4425x; 1.0814x over previous
//
#include <hip/hip_runtime.h>
#include <hip/hip_bf16.h>

#define NN 6144
#define FEATN 128
#define INSM 512
#define HIDN 256
#define DOUT 64

typedef _Float16 h4v __attribute__((ext_vector_type(4)));
typedef _Float16 h8v __attribute__((ext_vector_type(8)));
typedef float f32x4 __attribute__((ext_vector_type(4)));

// Weight-pack offsets (in halves) inside the contiguous wpk buffer.
#define O_W0L 0
#define O_W0S 65536
#define O_W0H 327680
#define O_W1L 589824
#define O_W1S 622592
#define O_W1H 655360
#define WPK_HALVES 688128

// ---------------------------------------------------------------------------
// Pack the 6 weight matrices to fp16 hi/lo in MFMA B-fragment k-major layout.
// ---------------------------------------------------------------------------
__global__ __launch_bounds__(256) void pack_w_kernel(
    const float* __restrict__ W0l, const float* __restrict__ W0s_,
    const float* __restrict__ W0h, const float* __restrict__ W1l,
    const float* __restrict__ W1s_, const float* __restrict__ W1h,
    _Float16* __restrict__ pk)
{
    const int id = blockIdx.y;
    const float* src; int K, N, offhi;
    switch (id) {
        case 0:  src = W0l;  K = 128; N = 256; offhi = O_W0L; break;
        case 1:  src = W0s_; K = 512; N = 256; offhi = O_W0S; break;
        case 2:  src = W0h;  K = 512; N = 256; offhi = O_W0H; break;
        case 3:  src = W1l;  K = 256; N = 64;  offhi = O_W1L; break;
        case 4:  src = W1s_; K = 256; N = 64;  offhi = O_W1S; break;
        default: src = W1h;  K = 256; N = 64;  offhi = O_W1H; break;
    }
    const int cnt = (K * N) >> 3;
    const int idx = blockIdx.x * 256 + threadIdx.x;
    if (idx >= cnt) return;
    const int col  = (N == 256) ? (idx & 255) : (idx & 63);
    const int kblk = (N == 256) ? (idx >> 8) : (idx >> 6);
    h8v hi, lo;
    #pragma unroll
    for (int e = 0; e < 8; ++e) {
        float x = src[(size_t)(kblk * 8 + e) * N + col];
        _Float16 h = (_Float16)x;
        hi[e] = h;
        lo[e] = (_Float16)(x - (float)h);
    }
    *reinterpret_cast<h8v*>(&pk[(size_t)offhi + (size_t)idx * 8]) = hi;
    *reinterpret_cast<h8v*>(&pk[(size_t)offhi + (size_t)(K * N) + (size_t)idx * 8]) = lo;
}

// ---------------------------------------------------------------------------
// MFMA MLP, 32-row tiles (proven round 11). br==2 epilogue now ALSO packs
// ehi/elo (from vals) and uphi/uplo (from uvals) directly — replaces the
// emb_split / ut_split kernels. f32 ut kept for colsum only.
// ---------------------------------------------------------------------------
__global__ __launch_bounds__(256) void mlp2_kernel(
    const float* __restrict__ ori, const float* __restrict__ sm,
    const _Float16* __restrict__ pk,
    const float* __restrict__ b0l, const float* __restrict__ b0s,
    const float* __restrict__ b0h, const float* __restrict__ b1l,
    const float* __restrict__ b1s, const float* __restrict__ b1h,
    const float* __restrict__ am_p, const float* __restrict__ ah_p,
    float* __restrict__ out, float* __restrict__ emb, float* __restrict__ ut,
    _Float16* __restrict__ ehi, _Float16* __restrict__ elo,
    _Float16* __restrict__ uphi, _Float16* __restrict__ uplo)
{
    __shared__ __align__(16) char smem[32 * 264 * 4];   // 33792 B
    float* xs    = (float*)smem;            // [2][32][32] dbuf (layer1)
    float* hs    = (float*)smem;            // [32][264] (layer2)
    float* vals  = (float*)smem;            // [32][65] logits (br2)
    float* uvals = (float*)(smem + 16384);  // [32][65] u rows (br2)

    const int t = threadIdx.x;
    const int br = blockIdx.y;
    const int r0 = blockIdx.x * 32;
    const int w = t >> 6, lane = t & 63, arow = lane & 15, ag = lane >> 4;

    const float* X;
    const _Float16 *B0hi, *B0lo, *B1hi, *B1lo;
    const float *bias0, *bias1;
    int K1; float alpha;
    if (br == 0) {
        X = ori; B0hi = pk + O_W0L; B0lo = B0hi + 128 * 256;
        B1hi = pk + O_W1L; B1lo = B1hi + 256 * 64;
        bias0 = b0l; bias1 = b1l; K1 = FEATN; alpha = am_p[0];
    } else if (br == 1) {
        X = sm; B0hi = pk + O_W0S; B0lo = B0hi + 512 * 256;
        B1hi = pk + O_W1S; B1lo = B1hi + 256 * 64;
        bias0 = b0s; bias1 = b1s; K1 = INSM; alpha = am_p[0];
    } else {
        X = sm; B0hi = pk + O_W0H; B0lo = B0hi + 512 * 256;
        B1hi = pk + O_W1H; B1lo = B1hi + 256 * 64;
        bias0 = b0h; bias1 = b1h; K1 = INSM; alpha = ah_p[0];
    }
    const int nks = K1 >> 5;

    // ---- layer 1 ----
    const int srow = t >> 3, sseg = t & 7;
    const float* Xrow = X + (size_t)(r0 + srow) * K1 + sseg * 4;
    {
        float4 a = *reinterpret_cast<const float4*>(Xrow);
        *reinterpret_cast<float4*>(&xs[(0 * 32 + srow) * 32 + sseg * 4]) = a;
    }
    __syncthreads();

    f32x4 acc1[2][4] = {};
    for (int ks = 0; ks < nks; ++ks) {
        const int buf = ks & 1;
        if (ks + 1 < nks) {
            float4 a = *reinterpret_cast<const float4*>(Xrow + (ks + 1) * 32);
            *reinterpret_cast<float4*>(
                &xs[((buf ^ 1) * 32 + srow) * 32 + sseg * 4]) = a;
        }
        h8v ahi[2], alo[2];
        #pragma unroll
        for (int rt = 0; rt < 2; ++rt) {
            const float* ap = &xs[(buf * 32 + rt * 16 + arow) * 32 + ag * 8];
            float4 a = *reinterpret_cast<const float4*>(ap);
            float4 b = *reinterpret_cast<const float4*>(ap + 4);
            float fv[8] = {a.x, a.y, a.z, a.w, b.x, b.y, b.z, b.w};
            #pragma unroll
            for (int e = 0; e < 8; ++e) {
                _Float16 h = (_Float16)fv[e];
                ahi[rt][e] = h;
                alo[rt][e] = (_Float16)(fv[e] - (float)h);
            }
        }
        #pragma unroll
        for (int ct = 0; ct < 4; ++ct) {
            const size_t bidx =
                ((size_t)(ks * 4 + ag) * 256 + w * 64 + ct * 16 + arow) * 8;
            h8v bhi = *reinterpret_cast<const h8v*>(&B0hi[bidx]);
            h8v blo = *reinterpret_cast<const h8v*>(&B0lo[bidx]);
            #pragma unroll
            for (int rt = 0; rt < 2; ++rt) {
                acc1[rt][ct] = __builtin_amdgcn_mfma_f32_16x16x32_f16(ahi[rt], bhi, acc1[rt][ct], 0, 0, 0);
                acc1[rt][ct] = __builtin_amdgcn_mfma_f32_16x16x32_f16(ahi[rt], blo, acc1[rt][ct], 0, 0, 0);
                acc1[rt][ct] = __builtin_amdgcn_mfma_f32_16x16x32_f16(alo[rt], bhi, acc1[rt][ct], 0, 0, 0);
            }
        }
        __syncthreads();
    }

    #pragma unroll
    for (int ct = 0; ct < 4; ++ct) {
        const int col = w * 64 + ct * 16 + arow;
        const float bb = bias0[col];
        #pragma unroll
        for (int rt = 0; rt < 2; ++rt)
            #pragma unroll
            for (int r = 0; r < 4; ++r) {
                float h = acc1[rt][ct][r] + bb;
                hs[(rt * 16 + ag * 4 + r) * 264 + col] = (h >= 0.f) ? h : alpha * h;
            }
    }
    __syncthreads();

    // ---- layer 2 ----
    f32x4 acc2[2] = {};
    #pragma unroll
    for (int ks2 = 0; ks2 < 8; ++ks2) {
        const size_t bidx = ((size_t)(ks2 * 4 + ag) * 64 + w * 16 + arow) * 8;
        h8v bhi = *reinterpret_cast<const h8v*>(&B1hi[bidx]);
        h8v blo = *reinterpret_cast<const h8v*>(&B1lo[bidx]);
        #pragma unroll
        for (int rt = 0; rt < 2; ++rt) {
            const float* ap = &hs[(rt * 16 + arow) * 264 + ks2 * 32 + ag * 8];
            float4 a = *reinterpret_cast<const float4*>(ap);
            float4 b = *reinterpret_cast<const float4*>(ap + 4);
            float fv[8] = {a.x, a.y, a.z, a.w, b.x, b.y, b.z, b.w};
            h8v ahi8, alo8;
            #pragma unroll
            for (int e = 0; e < 8; ++e) {
                _Float16 h = (_Float16)fv[e];
                ahi8[e] = h;
                alo8[e] = (_Float16)(fv[e] - (float)h);
            }
            acc2[rt] = __builtin_amdgcn_mfma_f32_16x16x32_f16(ahi8, bhi, acc2[rt], 0, 0, 0);
            acc2[rt] = __builtin_amdgcn_mfma_f32_16x16x32_f16(ahi8, blo, acc2[rt], 0, 0, 0);
            acc2[rt] = __builtin_amdgcn_mfma_f32_16x16x32_f16(alo8, bhi, acc2[rt], 0, 0, 0);
        }
    }

    const int col2 = w * 16 + arow;
    const float bb1 = bias1[col2];
    if (br < 2) {
        float* dst = out + (size_t)br * NN * DOUT;
        #pragma unroll
        for (int rt = 0; rt < 2; ++rt)
            #pragma unroll
            for (int r = 0; r < 4; ++r)
                dst[(size_t)(r0 + rt * 16 + ag * 4 + r) * 64 + col2] =
                    acc2[rt][r] + bb1;
    } else {
        __syncthreads();                        // hs reads done; vals aliases
        #pragma unroll
        for (int rt = 0; rt < 2; ++rt)
            #pragma unroll
            for (int r = 0; r < 4; ++r)
                vals[(rt * 16 + ag * 4 + r) * 65 + col2] = acc2[rt][r] + bb1;
        __syncthreads();
        // row softmax + L2 normalize; wave w owns rows w*8..+7
        for (int rr = 0; rr < 8; ++rr) {
            const int row = w * 8 + rr;
            float v = vals[row * 65 + lane];
            float mv = v;
            for (int off = 32; off > 0; off >>= 1) mv = fmaxf(mv, __shfl_xor(mv, off));
            float e = expf(v - mv);
            float ssum = e;
            for (int off = 32; off > 0; off >>= 1) ssum += __shfl_xor(ssum, off);
            float s = e / ssum;
            float n2 = s * s;
            for (int off = 32; off > 0; off >>= 1) n2 += __shfl_xor(n2, off);
            float uu = s * rsqrtf(n2);    // d_i >= 1/64 so max(.,1e-9) never binds
            emb[(size_t)(r0 + row) * 64 + lane] = v;
            ut[(size_t)lane * NN + (r0 + row)] = uu;   // f32, for colsum
            uvals[row * 65 + lane] = uu;
        }
        __syncthreads();                        // uvals ready; vals intact
        {   // pack ehi/elo from vals: thread -> (jb 0..3, c 0..63)
            const int jb = t >> 6, c = t & 63;
            h8v hi, lo;
            #pragma unroll
            for (int e = 0; e < 8; ++e) {
                float x = vals[(jb * 8 + e) * 65 + c];
                _Float16 h = (_Float16)x;
                hi[e] = h;
                lo[e] = (_Float16)(x - (float)h);
            }
            const size_t o = ((size_t)(r0 / 8 + jb) * 64 + c) * 8;
            *reinterpret_cast<h8v*>(&ehi[o]) = hi;
            *reinterpret_cast<h8v*>(&elo[o]) = lo;
        }
        {   // pack uphi/uplo from uvals: thread -> (kb 0..7, i 0..31)
            const int kb = t >> 5, i = t & 31;
            h8v hi, lo;
            #pragma unroll
            for (int e = 0; e < 8; ++e) {
                float x = uvals[i * 65 + kb * 8 + e];
                _Float16 h = (_Float16)x;
                hi[e] = h;
                lo[e] = (_Float16)(x - (float)h);
            }
            const size_t o = ((size_t)kb * NN + r0 + i) * 8;
            *reinterpret_cast<h8v*>(&uphi[o]) = hi;
            *reinterpret_cast<h8v*>(&uplo[o]) = lo;
        }
    }
}

// ---------------------------------------------------------------------------
// Column sums of u (= row sums of ut) in f64.
// ---------------------------------------------------------------------------
__global__ __launch_bounds__(256) void colsum_kernel(const float* __restrict__ ut,
                                                     double* __restrict__ colsum)
{
    __shared__ double cred[4];
    const int c = blockIdx.x, t = threadIdx.x;
    double a = 0.0;
    for (int i = t; i < NN; i += 256) a += (double)ut[(size_t)c * NN + i];
    for (int off = 32; off > 0; off >>= 1) a += __shfl_xor(a, off);
    if ((t & 63) == 0) cred[t >> 6] = a;
    __syncthreads();
    if (t == 0) colsum[c] = cred[0] + cred[1] + cred[2] + cred[3];
}

// ---------------------------------------------------------------------------
// MFMA max pass: max_{i!=j} R_ij, upper triangle. A/B fragments loaded
// DIRECTLY from uphi/uplo (bitwise-same hi/lo values as the old staging).
// ---------------------------------------------------------------------------
__global__ __launch_bounds__(256) void max5_kernel(
    const _Float16* __restrict__ uphi, const _Float16* __restrict__ uplo,
    unsigned int* __restrict__ mx)
{
    const int ti = blockIdx.x, tj = blockIdx.y;
    if (tj < ti) return;
    __shared__ float red[4];
    const int t = threadIdx.x;
    const int w = t >> 6, l = t & 63, arow = l & 15, ag = l >> 4;
    f32x4 acc[4] = {};
    #pragma unroll
    for (int ks = 0; ks < 2; ++ks) {
        const size_t bo = ((size_t)(ks * 4 + ag) * NN + tj * 64 + w * 16 + arow) * 8;
        h8v bhi = *reinterpret_cast<const h8v*>(&uphi[bo]);
        h8v blo = *reinterpret_cast<const h8v*>(&uplo[bo]);
        #pragma unroll
        for (int rt = 0; rt < 4; ++rt) {
            const size_t ao = ((size_t)(ks * 4 + ag) * NN + ti * 64 + rt * 16 + arow) * 8;
            h8v ahi_ = *reinterpret_cast<const h8v*>(&uphi[ao]);
            h8v alo_ = *reinterpret_cast<const h8v*>(&uplo[ao]);
            acc[rt] = __builtin_amdgcn_mfma_f32_16x16x32_f16(ahi_, bhi, acc[rt], 0, 0, 0);
            acc[rt] = __builtin_amdgcn_mfma_f32_16x16x32_f16(ahi_, blo, acc[rt], 0, 0, 0);
            acc[rt] = __builtin_amdgcn_mfma_f32_16x16x32_f16(alo_, bhi, acc[rt], 0, 0, 0);
        }
    }
    float lm = 0.f;
    const int gj = tj * 64 + w * 16 + arow;
    #pragma unroll
    for (int rt = 0; rt < 4; ++rt)
        #pragma unroll
        for (int r = 0; r < 4; ++r) {
            const int gi = ti * 64 + rt * 16 + ag * 4 + r;
            if (gi != gj) lm = fmaxf(lm, acc[rt][r]);
        }
    for (int off = 32; off > 0; off >>= 1) lm = fmaxf(lm, __shfl_xor(lm, off));
    if ((t & 63) == 0) red[t >> 6] = lm;
    __syncthreads();
    if (t == 0) {
        float bm = fmaxf(fmaxf(red[0], red[1]), fmaxf(red[2], red[3]));
        atomicMax(mx, __float_as_uint(bm));
    }
}

__global__ void finalize_kernel(const double* __restrict__ colsum,
                                const unsigned int* __restrict__ mx,
                                float* __restrict__ scal)
{
    const int c = threadIdx.x;
    double cs = colsum[c];
    double s2 = cs * cs;
    for (int off = 32; off > 0; off >>= 1) s2 += __shfl_xor(s2, off);
    if (c == 0) {
        double md = (s2 - (double)NN) / ((double)NN * (double)NN);
        float mf = (float)md;
        float mxv = __uint_as_float(mx[0]);
        scal[0] = mf;
        scal[1] = 1.0f / (mxv - mf);
        scal[2] = 1.0f / mf;
    }
}

// ---------------------------------------------------------------------------
// Fused propagation v5: grid (384, 4), 128-j tiles (12 per quarter).
// Producer computes R^T fragments (A=u_j, B=u_i; R symmetric) so each thread
// holds 4 CONSECUTIVE j -> one ds_write_b64 per array. Only vhi/phi stored
// (2-term PL GEMMs: logits = hi * (Bhi+Blo); R stays 3-term split).
// LDS 16 KB -> 6 blocks/CU. One barrier per tile (dbuf). setprio on MFMA.
// ---------------------------------------------------------------------------
__global__ __launch_bounds__(256) void prop5_kernel(
    const _Float16* __restrict__ uphi, const _Float16* __restrict__ uplo,
    const _Float16* __restrict__ ehi, const _Float16* __restrict__ elo,
    const float* __restrict__ scal, const float* __restrict__ ah_p,
    float* __restrict__ part)
{
    __shared__ __align__(16) _Float16 Abuf[2][2][16 * 128];  // 16 KB

    const int t = threadIdx.x;
    const int bi = blockIdx.x;
    const int q = blockIdx.y;
    const int gi0 = bi * 16;
    const float m = scal[0], inv_pd = scal[1], inv_m = scal[2];
    const float alpha = ah_p[0];

    const int w = t >> 6, l = t & 63, arow = l & 15, ag = l >> 4;
    const int col = w * 16 + arow;           // output c index
    const int gi = gi0 + arow;               // producer's i

    // B-frags for R^T (i-side), fixed per block
    h8v ubhi[2], ublo[2];
    #pragma unroll
    for (int ks = 0; ks < 2; ++ks) {
        const size_t o = ((size_t)(ks * 4 + ag) * NN + gi0 + arow) * 8;
        ubhi[ks] = *reinterpret_cast<const h8v*>(&uphi[o]);
        ublo[ks] = *reinterpret_cast<const h8v*>(&uplo[o]);
    }

    f32x4 accP = {0.f, 0.f, 0.f, 0.f};
    f32x4 accL = {0.f, 0.f, 0.f, 0.f};

    const int jt0 = q * 12, jt1 = jt0 + 12;
    for (int jt = jt0; jt < jt1; ++jt) {
        const int buf = jt & 1;
        char* base = (char*)&Abuf[buf][0][0];
        // ---- producer: 2 j-fragments (f = 2w, 2w+1), R^T via MFMA ----
        #pragma unroll
        for (int ff = 0; ff < 2; ++ff) {
            const int f = w * 2 + ff;
            const int j0 = jt * 128 + f * 16;
            f32x4 aR0 = {0.f, 0.f, 0.f, 0.f};
            f32x4 aR1 = {0.f, 0.f, 0.f, 0.f};
            {
                const size_t o = ((size_t)ag * NN + j0 + arow) * 8;
                h8v jh = *reinterpret_cast<const h8v*>(&uphi[o]);
                h8v jl = *reinterpret_cast<const h8v*>(&uplo[o]);
                aR0 = __builtin_amdgcn_mfma_f32_16x16x32_f16(jh, ubhi[0], aR0, 0, 0, 0);
                aR0 = __builtin_amdgcn_mfma_f32_16x16x32_f16(jh, ublo[0], aR0, 0, 0, 0);
                aR0 = __builtin_amdgcn_mfma_f32_16x16x32_f16(jl, ubhi[0], aR0, 0, 0, 0);
            }
            {
                const size_t o = ((size_t)(4 + ag) * NN + j0 + arow) * 8;
                h8v jh = *reinterpret_cast<const h8v*>(&uphi[o]);
                h8v jl = *reinterpret_cast<const h8v*>(&uplo[o]);
                aR1 = __builtin_amdgcn_mfma_f32_16x16x32_f16(jh, ubhi[1], aR1, 0, 0, 0);
                aR1 = __builtin_amdgcn_mfma_f32_16x16x32_f16(jh, ublo[1], aR1, 0, 0, 0);
                aR1 = __builtin_amdgcn_mfma_f32_16x16x32_f16(jl, ubhi[1], aR1, 0, 0, 0);
            }
            // transform 4 consecutive j (rows of R^T frag) for my i
            h4v vh4, ph4;
            #pragma unroll
            for (int r = 0; r < 4; ++r) {
                const int gj = j0 + ag * 4 + r;
                float rv = aR0[r] + aR1[r];
                float lre = (gi == gj) ? 0.f : rv;
                float x = lre - m;
                float v = (x > 0.f) ? x * inv_pd : -(lre * inv_m);
                if (gi == gj) v += 1.f;              // add_diag after where
                float p = (v >= 0.f) ? v : alpha * v;
                vh4[r] = (_Float16)v;
                ph4[r] = (_Float16)p;
            }
            const int gl = f * 2 + (ag >> 1);        // j-granule 0..15
            const int byte = arow * 256 + ((gl ^ (arow & 15)) << 4) + ((ag & 1) << 3);
            *reinterpret_cast<h4v*>(base + byte) = vh4;
            *reinterpret_cast<h4v*>(base + 4096 + byte) = ph4;
        }
        __syncthreads();        // single barrier per tile (dbuf-safe)

        // ---- consumer: P/L logit MFMAs (2-term) ----
        const char* cbase = (const char*)&Abuf[buf][0][0];
        __builtin_amdgcn_s_setprio(1);
        #pragma unroll
        for (int ks = 0; ks < 4; ++ks) {
            const int abyte = arow * 256 + (((ks * 4 + ag) ^ (arow & 15)) << 4);
            h8v vhiF = *reinterpret_cast<const h8v*>(cbase + abyte);
            h8v phiF = *reinterpret_cast<const h8v*>(cbase + 4096 + abyte);
            const size_t bidx = ((size_t)(jt * 16 + ks * 4 + ag) * 64 + col) * 8;
            h8v Bhi = *reinterpret_cast<const h8v*>(&ehi[bidx]);
            h8v Blo = *reinterpret_cast<const h8v*>(&elo[bidx]);
            accP = __builtin_amdgcn_mfma_f32_16x16x32_f16(phiF, Bhi, accP, 0, 0, 0);
            accP = __builtin_amdgcn_mfma_f32_16x16x32_f16(phiF, Blo, accP, 0, 0, 0);
            accL = __builtin_amdgcn_mfma_f32_16x16x32_f16(vhiF, Bhi, accL, 0, 0, 0);
            accL = __builtin_amdgcn_mfma_f32_16x16x32_f16(vhiF, Blo, accL, 0, 0, 0);
        }
        __builtin_amdgcn_s_setprio(0);
    }

    // ---- write P/L partials for this quarter ----
    {
        float* pbase = &part[((size_t)q * NN + gi0) * 128];
        #pragma unroll
        for (int r = 0; r < 4; ++r) {
            const int row = ag * 4 + r;
            pbase[(size_t)row * 128 + col] = accP[r];
            pbase[(size_t)row * 128 + 64 + col] = accL[r];
        }
    }
}

// ---------------------------------------------------------------------------
// Combine quarters: P = sum, L = sum, N = P - (1+alpha)L, dual softmax,
// epilogue -> out3. 384 blocks x 16 rows (4 rows/wave).
// ---------------------------------------------------------------------------
__global__ __launch_bounds__(256) void combine4_kernel(
    const float* __restrict__ part, const float* __restrict__ emb,
    const float* __restrict__ ah_p, float* __restrict__ out3)
{
    const int t = threadIdx.x;
    const int w = t >> 6, l = t & 63;
    const int gi0 = blockIdx.x * 16;
    const float one_pa = 1.f + ah_p[0];
    #pragma unroll
    for (int rr = 0; rr < 4; ++rr) {
        const int gi = gi0 + w * 4 + rr;
        float zp = 0.f, zl = 0.f;
        #pragma unroll
        for (int q = 0; q < 4; ++q) {
            const float* p = &part[((size_t)q * NN + gi) * 128];
            zp += p[l];
            zl += p[64 + l];
        }
        float zn = zp - one_pa * zl;

        float mp = zp;
        for (int off = 32; off > 0; off >>= 1) mp = fmaxf(mp, __shfl_xor(mp, off));
        float ep = __expf(zp - mp);
        float sump = ep;
        for (int off = 32; off > 0; off >>= 1) sump += __shfl_xor(sump, off);
        float pp = ep / sump;

        float mn = zn;
        for (int off = 32; off > 0; off >>= 1) mn = fmaxf(mn, __shfl_xor(mn, off));
        float en = __expf(zn - mn);
        float sumn = en;
        for (int off = 32; off > 0; off >>= 1) sumn += __shfl_xor(sumn, off);
        float pn = en / sumn;

        out3[(size_t)gi * 64 + l] = 0.5f * (pp - pn + emb[(size_t)gi * 64 + l]);
    }
}

extern "C" void kernel_launch(void* const* d_in, const int* in_sizes, int n_in,
                              void* d_out, int out_size, void* d_ws, size_t ws_size,
                              hipStream_t stream)
{
    (void)in_sizes; (void)n_in; (void)out_size; (void)ws_size;
    const float* ori = (const float*)d_in[0];
    const float* sm  = (const float*)d_in[1];
    // d_in[2] processed_feature: unused; d_in[3] universal_re: unused (BETA=0)
    const float* W0s = (const float*)d_in[4];
    const float* b0s = (const float*)d_in[5];
    const float* W1s = (const float*)d_in[6];
    const float* b1s = (const float*)d_in[7];
    const float* W0l = (const float*)d_in[8];
    const float* b0l = (const float*)d_in[9];
    const float* W1l = (const float*)d_in[10];
    const float* b1l = (const float*)d_in[11];
    const float* W0h = (const float*)d_in[12];
    const float* b0h = (const float*)d_in[13];
    const float* W1h = (const float*)d_in[14];
    const float* b1h = (const float*)d_in[15];
    const float* amp = (const float*)d_in[16];
    const float* ahp = (const float*)d_in[17];

    float* out = (float*)d_out;                       // f32 output (ref dtype)
    float* ws = (float*)d_ws;
    float* emb = ws;                                  // NN*64 f32
    float* ut  = ws + (size_t)NN * DOUT;              // 64*NN f32 (colsum only)
    double* colsum = (double*)(ws + (size_t)2 * NN * DOUT);   // 64 f64
    unsigned int* mx = (unsigned int*)(ws + (size_t)2 * NN * DOUT + 128);
    float* scal = ws + (size_t)2 * NN * DOUT + 128 + 4;       // 3 f32
    size_t eh_off = (((size_t)2 * NN * DOUT + 128 + 8) + 15) & ~(size_t)15;
    _Float16* ehi = (_Float16*)(ws + eh_off);                 // NN*64 halves
    _Float16* elo = ehi + (size_t)NN * DOUT;
    size_t up_off = eh_off + (size_t)NN * DOUT;               // f32 words
    _Float16* uphi = (_Float16*)(ws + up_off);                // NN*64 halves
    _Float16* uplo = uphi + (size_t)NN * DOUT;
    size_t wpk_off = up_off + (size_t)NN * DOUT;
    _Float16* wpk = (_Float16*)(ws + wpk_off);                // 688128 halves
    size_t part_off = (wpk_off + WPK_HALVES / 2 + 15) & ~(size_t)15;
    float* part = ws + part_off;                              // 4*NN*128 f32
    // total ws footprint ~20.3 MB

    hipMemsetAsync(mx, 0, 4, stream);
    pack_w_kernel<<<dim3(64, 6), 256, 0, stream>>>(W0l, W0s, W0h, W1l, W1s, W1h, wpk);
    mlp2_kernel<<<dim3(NN / 32, 3), 256, 0, stream>>>(
        ori, sm, wpk, b0l, b0s, b0h, b1l, b1s, b1h, amp, ahp,
        out, emb, ut, ehi, elo, uphi, uplo);
    colsum_kernel<<<64, 256, 0, stream>>>(ut, colsum);
    max5_kernel<<<dim3(96, 96), 256, 0, stream>>>(uphi, uplo, mx);
    finalize_kernel<<<1, 64, 0, stream>>>(colsum, mx, scal);
    prop5_kernel<<<dim3(NN / 16, 4), 256, 0, stream>>>(
        uphi, uplo, ehi, elo, scal, ahp, part);
    combine4_kernel<<<NN / 16, 256, 0, stream>>>(
        part, emb, ahp, out + (size_t)2 * NN * DOUT);
}

// Round 13
// 171.964 us; speedup vs baseline: 1.5111x; 1.0475x over previous
//
#include <hip/hip_runtime.h>
#include <hip/hip_bf16.h>

#define NN 6144
#define FEATN 128
#define INSM 512
#define HIDN 256
#define DOUT 64

typedef _Float16 h4v __attribute__((ext_vector_type(4)));
typedef _Float16 h8v __attribute__((ext_vector_type(8)));
typedef float f32x4 __attribute__((ext_vector_type(4)));

// Weight-pack offsets (in halves) inside the contiguous wpk buffer.
#define O_W0L 0
#define O_W0S 65536
#define O_W0H 327680
#define O_W1L 589824
#define O_W1S 622592
#define O_W1H 655360
#define WPK_HALVES 688128

// ---------------------------------------------------------------------------
// Pack the 6 weight matrices to fp16 hi/lo in MFMA B-fragment k-major layout.
// ---------------------------------------------------------------------------
__global__ __launch_bounds__(256) void pack_w_kernel(
    const float* __restrict__ W0l, const float* __restrict__ W0s_,
    const float* __restrict__ W0h, const float* __restrict__ W1l,
    const float* __restrict__ W1s_, const float* __restrict__ W1h,
    _Float16* __restrict__ pk)
{
    const int id = blockIdx.y;
    const float* src; int K, N, offhi;
    switch (id) {
        case 0:  src = W0l;  K = 128; N = 256; offhi = O_W0L; break;
        case 1:  src = W0s_; K = 512; N = 256; offhi = O_W0S; break;
        case 2:  src = W0h;  K = 512; N = 256; offhi = O_W0H; break;
        case 3:  src = W1l;  K = 256; N = 64;  offhi = O_W1L; break;
        case 4:  src = W1s_; K = 256; N = 64;  offhi = O_W1S; break;
        default: src = W1h;  K = 256; N = 64;  offhi = O_W1H; break;
    }
    const int cnt = (K * N) >> 3;
    const int idx = blockIdx.x * 256 + threadIdx.x;
    if (idx >= cnt) return;
    const int col  = (N == 256) ? (idx & 255) : (idx & 63);
    const int kblk = (N == 256) ? (idx >> 8) : (idx >> 6);
    h8v hi, lo;
    #pragma unroll
    for (int e = 0; e < 8; ++e) {
        float x = src[(size_t)(kblk * 8 + e) * N + col];
        _Float16 h = (_Float16)x;
        hi[e] = h;
        lo[e] = (_Float16)(x - (float)h);
    }
    *reinterpret_cast<h8v*>(&pk[(size_t)offhi + (size_t)idx * 8]) = hi;
    *reinterpret_cast<h8v*>(&pk[(size_t)offhi + (size_t)(K * N) + (size_t)idx * 8]) = lo;
}

// ---------------------------------------------------------------------------
// MFMA MLP, 32-row tiles (proven round 11/12). br==2 epilogue packs
// ehi/elo and uphi/uplo directly. f32 ut kept for colsum only.
// ---------------------------------------------------------------------------
__global__ __launch_bounds__(256) void mlp2_kernel(
    const float* __restrict__ ori, const float* __restrict__ sm,
    const _Float16* __restrict__ pk,
    const float* __restrict__ b0l, const float* __restrict__ b0s,
    const float* __restrict__ b0h, const float* __restrict__ b1l,
    const float* __restrict__ b1s, const float* __restrict__ b1h,
    const float* __restrict__ am_p, const float* __restrict__ ah_p,
    float* __restrict__ out, float* __restrict__ emb, float* __restrict__ ut,
    _Float16* __restrict__ ehi, _Float16* __restrict__ elo,
    _Float16* __restrict__ uphi, _Float16* __restrict__ uplo)
{
    __shared__ __align__(16) char smem[32 * 264 * 4];   // 33792 B
    float* xs    = (float*)smem;            // [2][32][32] dbuf (layer1)
    float* hs    = (float*)smem;            // [32][264] (layer2)
    float* vals  = (float*)smem;            // [32][65] logits (br2)
    float* uvals = (float*)(smem + 16384);  // [32][65] u rows (br2)

    const int t = threadIdx.x;
    const int br = blockIdx.y;
    const int r0 = blockIdx.x * 32;
    const int w = t >> 6, lane = t & 63, arow = lane & 15, ag = lane >> 4;

    const float* X;
    const _Float16 *B0hi, *B0lo, *B1hi, *B1lo;
    const float *bias0, *bias1;
    int K1; float alpha;
    if (br == 0) {
        X = ori; B0hi = pk + O_W0L; B0lo = B0hi + 128 * 256;
        B1hi = pk + O_W1L; B1lo = B1hi + 256 * 64;
        bias0 = b0l; bias1 = b1l; K1 = FEATN; alpha = am_p[0];
    } else if (br == 1) {
        X = sm; B0hi = pk + O_W0S; B0lo = B0hi + 512 * 256;
        B1hi = pk + O_W1S; B1lo = B1hi + 256 * 64;
        bias0 = b0s; bias1 = b1s; K1 = INSM; alpha = am_p[0];
    } else {
        X = sm; B0hi = pk + O_W0H; B0lo = B0hi + 512 * 256;
        B1hi = pk + O_W1H; B1lo = B1hi + 256 * 64;
        bias0 = b0h; bias1 = b1h; K1 = INSM; alpha = ah_p[0];
    }
    const int nks = K1 >> 5;

    // ---- layer 1 ----
    const int srow = t >> 3, sseg = t & 7;
    const float* Xrow = X + (size_t)(r0 + srow) * K1 + sseg * 4;
    {
        float4 a = *reinterpret_cast<const float4*>(Xrow);
        *reinterpret_cast<float4*>(&xs[(0 * 32 + srow) * 32 + sseg * 4]) = a;
    }
    __syncthreads();

    f32x4 acc1[2][4] = {};
    for (int ks = 0; ks < nks; ++ks) {
        const int buf = ks & 1;
        if (ks + 1 < nks) {
            float4 a = *reinterpret_cast<const float4*>(Xrow + (ks + 1) * 32);
            *reinterpret_cast<float4*>(
                &xs[((buf ^ 1) * 32 + srow) * 32 + sseg * 4]) = a;
        }
        h8v ahi[2], alo[2];
        #pragma unroll
        for (int rt = 0; rt < 2; ++rt) {
            const float* ap = &xs[(buf * 32 + rt * 16 + arow) * 32 + ag * 8];
            float4 a = *reinterpret_cast<const float4*>(ap);
            float4 b = *reinterpret_cast<const float4*>(ap + 4);
            float fv[8] = {a.x, a.y, a.z, a.w, b.x, b.y, b.z, b.w};
            #pragma unroll
            for (int e = 0; e < 8; ++e) {
                _Float16 h = (_Float16)fv[e];
                ahi[rt][e] = h;
                alo[rt][e] = (_Float16)(fv[e] - (float)h);
            }
        }
        #pragma unroll
        for (int ct = 0; ct < 4; ++ct) {
            const size_t bidx =
                ((size_t)(ks * 4 + ag) * 256 + w * 64 + ct * 16 + arow) * 8;
            h8v bhi = *reinterpret_cast<const h8v*>(&B0hi[bidx]);
            h8v blo = *reinterpret_cast<const h8v*>(&B0lo[bidx]);
            #pragma unroll
            for (int rt = 0; rt < 2; ++rt) {
                acc1[rt][ct] = __builtin_amdgcn_mfma_f32_16x16x32_f16(ahi[rt], bhi, acc1[rt][ct], 0, 0, 0);
                acc1[rt][ct] = __builtin_amdgcn_mfma_f32_16x16x32_f16(ahi[rt], blo, acc1[rt][ct], 0, 0, 0);
                acc1[rt][ct] = __builtin_amdgcn_mfma_f32_16x16x32_f16(alo[rt], bhi, acc1[rt][ct], 0, 0, 0);
            }
        }
        __syncthreads();
    }

    #pragma unroll
    for (int ct = 0; ct < 4; ++ct) {
        const int col = w * 64 + ct * 16 + arow;
        const float bb = bias0[col];
        #pragma unroll
        for (int rt = 0; rt < 2; ++rt)
            #pragma unroll
            for (int r = 0; r < 4; ++r) {
                float h = acc1[rt][ct][r] + bb;
                hs[(rt * 16 + ag * 4 + r) * 264 + col] = (h >= 0.f) ? h : alpha * h;
            }
    }
    __syncthreads();

    // ---- layer 2 ----
    f32x4 acc2[2] = {};
    #pragma unroll
    for (int ks2 = 0; ks2 < 8; ++ks2) {
        const size_t bidx = ((size_t)(ks2 * 4 + ag) * 64 + w * 16 + arow) * 8;
        h8v bhi = *reinterpret_cast<const h8v*>(&B1hi[bidx]);
        h8v blo = *reinterpret_cast<const h8v*>(&B1lo[bidx]);
        #pragma unroll
        for (int rt = 0; rt < 2; ++rt) {
            const float* ap = &hs[(rt * 16 + arow) * 264 + ks2 * 32 + ag * 8];
            float4 a = *reinterpret_cast<const float4*>(ap);
            float4 b = *reinterpret_cast<const float4*>(ap + 4);
            float fv[8] = {a.x, a.y, a.z, a.w, b.x, b.y, b.z, b.w};
            h8v ahi8, alo8;
            #pragma unroll
            for (int e = 0; e < 8; ++e) {
                _Float16 h = (_Float16)fv[e];
                ahi8[e] = h;
                alo8[e] = (_Float16)(fv[e] - (float)h);
            }
            acc2[rt] = __builtin_amdgcn_mfma_f32_16x16x32_f16(ahi8, bhi, acc2[rt], 0, 0, 0);
            acc2[rt] = __builtin_amdgcn_mfma_f32_16x16x32_f16(ahi8, blo, acc2[rt], 0, 0, 0);
            acc2[rt] = __builtin_amdgcn_mfma_f32_16x16x32_f16(alo8, bhi, acc2[rt], 0, 0, 0);
        }
    }

    const int col2 = w * 16 + arow;
    const float bb1 = bias1[col2];
    if (br < 2) {
        float* dst = out + (size_t)br * NN * DOUT;
        #pragma unroll
        for (int rt = 0; rt < 2; ++rt)
            #pragma unroll
            for (int r = 0; r < 4; ++r)
                dst[(size_t)(r0 + rt * 16 + ag * 4 + r) * 64 + col2] =
                    acc2[rt][r] + bb1;
    } else {
        __syncthreads();                        // hs reads done; vals aliases
        #pragma unroll
        for (int rt = 0; rt < 2; ++rt)
            #pragma unroll
            for (int r = 0; r < 4; ++r)
                vals[(rt * 16 + ag * 4 + r) * 65 + col2] = acc2[rt][r] + bb1;
        __syncthreads();
        // row softmax + L2 normalize; wave w owns rows w*8..+7
        for (int rr = 0; rr < 8; ++rr) {
            const int row = w * 8 + rr;
            float v = vals[row * 65 + lane];
            float mv = v;
            for (int off = 32; off > 0; off >>= 1) mv = fmaxf(mv, __shfl_xor(mv, off));
            float e = expf(v - mv);
            float ssum = e;
            for (int off = 32; off > 0; off >>= 1) ssum += __shfl_xor(ssum, off);
            float s = e / ssum;
            float n2 = s * s;
            for (int off = 32; off > 0; off >>= 1) n2 += __shfl_xor(n2, off);
            float uu = s * rsqrtf(n2);    // d_i >= 1/64 so max(.,1e-9) never binds
            emb[(size_t)(r0 + row) * 64 + lane] = v;
            ut[(size_t)lane * NN + (r0 + row)] = uu;   // f32, for colsum
            uvals[row * 65 + lane] = uu;
        }
        __syncthreads();                        // uvals ready; vals intact
        {   // pack ehi/elo from vals
            const int jb = t >> 6, c = t & 63;
            h8v hi, lo;
            #pragma unroll
            for (int e = 0; e < 8; ++e) {
                float x = vals[(jb * 8 + e) * 65 + c];
                _Float16 h = (_Float16)x;
                hi[e] = h;
                lo[e] = (_Float16)(x - (float)h);
            }
            const size_t o = ((size_t)(r0 / 8 + jb) * 64 + c) * 8;
            *reinterpret_cast<h8v*>(&ehi[o]) = hi;
            *reinterpret_cast<h8v*>(&elo[o]) = lo;
        }
        {   // pack uphi/uplo from uvals
            const int kb = t >> 5, i = t & 31;
            h8v hi, lo;
            #pragma unroll
            for (int e = 0; e < 8; ++e) {
                float x = uvals[i * 65 + kb * 8 + e];
                _Float16 h = (_Float16)x;
                hi[e] = h;
                lo[e] = (_Float16)(x - (float)h);
            }
            const size_t o = ((size_t)kb * NN + r0 + i) * 8;
            *reinterpret_cast<h8v*>(&uphi[o]) = hi;
            *reinterpret_cast<h8v*>(&uplo[o]) = lo;
        }
    }
}

// ---------------------------------------------------------------------------
// Column sums of u (= row sums of ut) in f64.
// ---------------------------------------------------------------------------
__global__ __launch_bounds__(256) void colsum_kernel(const float* __restrict__ ut,
                                                     double* __restrict__ colsum)
{
    __shared__ double cred[4];
    const int c = blockIdx.x, t = threadIdx.x;
    double a = 0.0;
    for (int i = t; i < NN; i += 256) a += (double)ut[(size_t)c * NN + i];
    for (int off = 32; off > 0; off >>= 1) a += __shfl_xor(a, off);
    if ((t & 63) == 0) cred[t >> 6] = a;
    __syncthreads();
    if (t == 0) colsum[c] = cred[0] + cred[1] + cred[2] + cred[3];
}

// ---------------------------------------------------------------------------
// MFMA max pass: max_{i!=j} R_ij, upper triangle (proven round 12).
// ---------------------------------------------------------------------------
__global__ __launch_bounds__(256) void max5_kernel(
    const _Float16* __restrict__ uphi, const _Float16* __restrict__ uplo,
    unsigned int* __restrict__ mx)
{
    const int ti = blockIdx.x, tj = blockIdx.y;
    if (tj < ti) return;
    __shared__ float red[4];
    const int t = threadIdx.x;
    const int w = t >> 6, l = t & 63, arow = l & 15, ag = l >> 4;
    f32x4 acc[4] = {};
    #pragma unroll
    for (int ks = 0; ks < 2; ++ks) {
        const size_t bo = ((size_t)(ks * 4 + ag) * NN + tj * 64 + w * 16 + arow) * 8;
        h8v bhi = *reinterpret_cast<const h8v*>(&uphi[bo]);
        h8v blo = *reinterpret_cast<const h8v*>(&uplo[bo]);
        #pragma unroll
        for (int rt = 0; rt < 4; ++rt) {
            const size_t ao = ((size_t)(ks * 4 + ag) * NN + ti * 64 + rt * 16 + arow) * 8;
            h8v ahi_ = *reinterpret_cast<const h8v*>(&uphi[ao]);
            h8v alo_ = *reinterpret_cast<const h8v*>(&uplo[ao]);
            acc[rt] = __builtin_amdgcn_mfma_f32_16x16x32_f16(ahi_, bhi, acc[rt], 0, 0, 0);
            acc[rt] = __builtin_amdgcn_mfma_f32_16x16x32_f16(ahi_, blo, acc[rt], 0, 0, 0);
            acc[rt] = __builtin_amdgcn_mfma_f32_16x16x32_f16(alo_, bhi, acc[rt], 0, 0, 0);
        }
    }
    float lm = 0.f;
    const int gj = tj * 64 + w * 16 + arow;
    #pragma unroll
    for (int rt = 0; rt < 4; ++rt)
        #pragma unroll
        for (int r = 0; r < 4; ++r) {
            const int gi = ti * 64 + rt * 16 + ag * 4 + r;
            if (gi != gj) lm = fmaxf(lm, acc[rt][r]);
        }
    for (int off = 32; off > 0; off >>= 1) lm = fmaxf(lm, __shfl_xor(lm, off));
    if ((t & 63) == 0) red[t >> 6] = lm;
    __syncthreads();
    if (t == 0) {
        float bm = fmaxf(fmaxf(red[0], red[1]), fmaxf(red[2], red[3]));
        atomicMax(mx, __float_as_uint(bm));
    }
}

__global__ void finalize_kernel(const double* __restrict__ colsum,
                                const unsigned int* __restrict__ mx,
                                float* __restrict__ scal)
{
    const int c = threadIdx.x;
    double cs = colsum[c];
    double s2 = cs * cs;
    for (int off = 32; off > 0; off >>= 1) s2 += __shfl_xor(s2, off);
    if (c == 0) {
        double md = (s2 - (double)NN) / ((double)NN * (double)NN);
        float mf = (float)md;
        float mxv = __uint_as_float(mx[0]);
        scal[0] = mf;
        scal[1] = 1.0f / (mxv - mf);
        scal[2] = 1.0f / mf;
    }
}

// ---------------------------------------------------------------------------
// Fused propagation v6: 32 i-rows/block, grid (192, 8), 128-j tiles (6/q).
// j-side u loads and e B-frags are loaded once per tile and reused for BOTH
// i-halves (halves the cross-block-redundant L2 traffic vs prop5).
// Producer: R^T fragments (A=u_j, B=u_i[ih]); thread holds 4 consecutive j
// -> ds_write_b64. Only vhi/phi stored (2-term PL; R stays 3-term).
// LDS 32 KB dbuf, 1 barrier/tile, setprio on consumer MFMAs.
// ---------------------------------------------------------------------------
__global__ __launch_bounds__(256, 4) void prop6_kernel(
    const _Float16* __restrict__ uphi, const _Float16* __restrict__ uplo,
    const _Float16* __restrict__ ehi, const _Float16* __restrict__ elo,
    const float* __restrict__ scal, const float* __restrict__ ah_p,
    float* __restrict__ part)
{
    __shared__ __align__(16) _Float16 Abuf[2][2][32 * 128];  // 32 KB

    const int t = threadIdx.x;
    const int bi = blockIdx.x;
    const int q = blockIdx.y;
    const int gi0 = bi * 32;
    const float m = scal[0], inv_pd = scal[1], inv_m = scal[2];
    const float alpha = ah_p[0];

    const int w = t >> 6, l = t & 63, arow = l & 15, ag = l >> 4;
    const int col = w * 16 + arow;           // output c index

    // B-frags for R^T (i-side), both i-halves, fixed per block
    h8v ubhi[2][2], ublo[2][2];              // [ks][ih]
    #pragma unroll
    for (int ks = 0; ks < 2; ++ks)
        #pragma unroll
        for (int ih = 0; ih < 2; ++ih) {
            const size_t o = ((size_t)(ks * 4 + ag) * NN + gi0 + ih * 16 + arow) * 8;
            ubhi[ks][ih] = *reinterpret_cast<const h8v*>(&uphi[o]);
            ublo[ks][ih] = *reinterpret_cast<const h8v*>(&uplo[o]);
        }

    f32x4 accP[2] = {};
    f32x4 accL[2] = {};

    const int jt0 = q * 6, jt1 = jt0 + 6;
    for (int jt = jt0; jt < jt1; ++jt) {
        const int buf = jt & 1;
        char* base = (char*)&Abuf[buf][0][0];
        // ---- producer: 2 j-fragments (f = 2w, 2w+1), R^T for both i-halves ----
        #pragma unroll
        for (int ff = 0; ff < 2; ++ff) {
            const int f = w * 2 + ff;
            const int j0 = jt * 128 + f * 16;
            // j-side loads once, shared across i-halves
            h8v jh0, jl0, jh1, jl1;
            {
                const size_t o0 = ((size_t)ag * NN + j0 + arow) * 8;
                jh0 = *reinterpret_cast<const h8v*>(&uphi[o0]);
                jl0 = *reinterpret_cast<const h8v*>(&uplo[o0]);
                const size_t o1 = ((size_t)(4 + ag) * NN + j0 + arow) * 8;
                jh1 = *reinterpret_cast<const h8v*>(&uphi[o1]);
                jl1 = *reinterpret_cast<const h8v*>(&uplo[o1]);
            }
            #pragma unroll
            for (int ih = 0; ih < 2; ++ih) {
                f32x4 aR0 = {0.f, 0.f, 0.f, 0.f};
                f32x4 aR1 = {0.f, 0.f, 0.f, 0.f};
                aR0 = __builtin_amdgcn_mfma_f32_16x16x32_f16(jh0, ubhi[0][ih], aR0, 0, 0, 0);
                aR0 = __builtin_amdgcn_mfma_f32_16x16x32_f16(jh0, ublo[0][ih], aR0, 0, 0, 0);
                aR0 = __builtin_amdgcn_mfma_f32_16x16x32_f16(jl0, ubhi[0][ih], aR0, 0, 0, 0);
                aR1 = __builtin_amdgcn_mfma_f32_16x16x32_f16(jh1, ubhi[1][ih], aR1, 0, 0, 0);
                aR1 = __builtin_amdgcn_mfma_f32_16x16x32_f16(jh1, ublo[1][ih], aR1, 0, 0, 0);
                aR1 = __builtin_amdgcn_mfma_f32_16x16x32_f16(jl1, ubhi[1][ih], aR1, 0, 0, 0);
                // transform 4 consecutive j for my i = gi0 + ih*16 + arow
                const int gi = gi0 + ih * 16 + arow;
                h4v vh4, ph4;
                #pragma unroll
                for (int r = 0; r < 4; ++r) {
                    const int gj = j0 + ag * 4 + r;
                    float rv = aR0[r] + aR1[r];
                    float lre = (gi == gj) ? 0.f : rv;
                    float x = lre - m;
                    float v = (x > 0.f) ? x * inv_pd : -(lre * inv_m);
                    if (gi == gj) v += 1.f;          // add_diag after where
                    float p = (v >= 0.f) ? v : alpha * v;
                    vh4[r] = (_Float16)v;
                    ph4[r] = (_Float16)p;
                }
                const int gl = f * 2 + (ag >> 1);    // j-granule 0..15
                const int byte = (ih * 16 + arow) * 256 +
                                 ((gl ^ (arow & 15)) << 4) + ((ag & 1) << 3);
                *reinterpret_cast<h4v*>(base + byte) = vh4;
                *reinterpret_cast<h4v*>(base + 8192 + byte) = ph4;
            }
        }
        __syncthreads();        // single barrier per tile (dbuf-safe)

        // ---- consumer: P/L logit MFMAs (2-term), both i-halves ----
        const char* cbase = (const char*)&Abuf[buf][0][0];
        __builtin_amdgcn_s_setprio(1);
        #pragma unroll
        for (int ks = 0; ks < 4; ++ks) {
            const size_t bidx = ((size_t)(jt * 16 + ks * 4 + ag) * 64 + col) * 8;
            h8v Bhi = *reinterpret_cast<const h8v*>(&ehi[bidx]);
            h8v Blo = *reinterpret_cast<const h8v*>(&elo[bidx]);
            #pragma unroll
            for (int ih = 0; ih < 2; ++ih) {
                const int abyte = (ih * 16 + arow) * 256 +
                                  (((ks * 4 + ag) ^ (arow & 15)) << 4);
                h8v vhiF = *reinterpret_cast<const h8v*>(cbase + abyte);
                h8v phiF = *reinterpret_cast<const h8v*>(cbase + 8192 + abyte);
                accP[ih] = __builtin_amdgcn_mfma_f32_16x16x32_f16(phiF, Bhi, accP[ih], 0, 0, 0);
                accP[ih] = __builtin_amdgcn_mfma_f32_16x16x32_f16(phiF, Blo, accP[ih], 0, 0, 0);
                accL[ih] = __builtin_amdgcn_mfma_f32_16x16x32_f16(vhiF, Bhi, accL[ih], 0, 0, 0);
                accL[ih] = __builtin_amdgcn_mfma_f32_16x16x32_f16(vhiF, Blo, accL[ih], 0, 0, 0);
            }
        }
        __builtin_amdgcn_s_setprio(0);
    }

    // ---- write P/L partials for this quarter ----
    {
        float* pbase = &part[((size_t)q * NN + gi0) * 128];
        #pragma unroll
        for (int ih = 0; ih < 2; ++ih)
            #pragma unroll
            for (int r = 0; r < 4; ++r) {
                const int row = ih * 16 + ag * 4 + r;
                pbase[(size_t)row * 128 + col] = accP[ih][r];
                pbase[(size_t)row * 128 + 64 + col] = accL[ih][r];
            }
    }
}

// ---------------------------------------------------------------------------
// Combine 8 partials: P = sum, L = sum, N = P - (1+alpha)L, dual softmax,
// epilogue -> out3. 384 blocks x 16 rows (4 rows/wave).
// ---------------------------------------------------------------------------
__global__ __launch_bounds__(256) void combine4_kernel(
    const float* __restrict__ part, const float* __restrict__ emb,
    const float* __restrict__ ah_p, float* __restrict__ out3)
{
    const int t = threadIdx.x;
    const int w = t >> 6, l = t & 63;
    const int gi0 = blockIdx.x * 16;
    const float one_pa = 1.f + ah_p[0];
    #pragma unroll
    for (int rr = 0; rr < 4; ++rr) {
        const int gi = gi0 + w * 4 + rr;
        float zp = 0.f, zl = 0.f;
        #pragma unroll
        for (int q = 0; q < 8; ++q) {
            const float* p = &part[((size_t)q * NN + gi) * 128];
            zp += p[l];
            zl += p[64 + l];
        }
        float zn = zp - one_pa * zl;

        float mp = zp;
        for (int off = 32; off > 0; off >>= 1) mp = fmaxf(mp, __shfl_xor(mp, off));
        float ep = __expf(zp - mp);
        float sump = ep;
        for (int off = 32; off > 0; off >>= 1) sump += __shfl_xor(sump, off);
        float pp = ep / sump;

        float mn = zn;
        for (int off = 32; off > 0; off >>= 1) mn = fmaxf(mn, __shfl_xor(mn, off));
        float en = __expf(zn - mn);
        float sumn = en;
        for (int off = 32; off > 0; off >>= 1) sumn += __shfl_xor(sumn, off);
        float pn = en / sumn;

        out3[(size_t)gi * 64 + l] = 0.5f * (pp - pn + emb[(size_t)gi * 64 + l]);
    }
}

extern "C" void kernel_launch(void* const* d_in, const int* in_sizes, int n_in,
                              void* d_out, int out_size, void* d_ws, size_t ws_size,
                              hipStream_t stream)
{
    (void)in_sizes; (void)n_in; (void)out_size; (void)ws_size;
    const float* ori = (const float*)d_in[0];
    const float* sm  = (const float*)d_in[1];
    // d_in[2] processed_feature: unused; d_in[3] universal_re: unused (BETA=0)
    const float* W0s = (const float*)d_in[4];
    const float* b0s = (const float*)d_in[5];
    const float* W1s = (const float*)d_in[6];
    const float* b1s = (const float*)d_in[7];
    const float* W0l = (const float*)d_in[8];
    const float* b0l = (const float*)d_in[9];
    const float* W1l = (const float*)d_in[10];
    const float* b1l = (const float*)d_in[11];
    const float* W0h = (const float*)d_in[12];
    const float* b0h = (const float*)d_in[13];
    const float* W1h = (const float*)d_in[14];
    const float* b1h = (const float*)d_in[15];
    const float* amp = (const float*)d_in[16];
    const float* ahp = (const float*)d_in[17];

    float* out = (float*)d_out;                       // f32 output (ref dtype)
    float* ws = (float*)d_ws;
    float* emb = ws;                                  // NN*64 f32
    float* ut  = ws + (size_t)NN * DOUT;              // 64*NN f32 (colsum only)
    double* colsum = (double*)(ws + (size_t)2 * NN * DOUT);   // 64 f64
    unsigned int* mx = (unsigned int*)(ws + (size_t)2 * NN * DOUT + 128);
    float* scal = ws + (size_t)2 * NN * DOUT + 128 + 4;       // 3 f32
    size_t eh_off = (((size_t)2 * NN * DOUT + 128 + 8) + 15) & ~(size_t)15;
    _Float16* ehi = (_Float16*)(ws + eh_off);                 // NN*64 halves
    _Float16* elo = ehi + (size_t)NN * DOUT;
    size_t up_off = eh_off + (size_t)NN * DOUT;               // f32 words
    _Float16* uphi = (_Float16*)(ws + up_off);                // NN*64 halves
    _Float16* uplo = uphi + (size_t)NN * DOUT;
    size_t wpk_off = up_off + (size_t)NN * DOUT;
    _Float16* wpk = (_Float16*)(ws + wpk_off);                // 688128 halves
    size_t part_off = (wpk_off + WPK_HALVES / 2 + 15) & ~(size_t)15;
    float* part = ws + part_off;                              // 8*NN*128 f32
    // total ws footprint ~33 MB

    hipMemsetAsync(mx, 0, 4, stream);
    pack_w_kernel<<<dim3(64, 6), 256, 0, stream>>>(W0l, W0s, W0h, W1l, W1s, W1h, wpk);
    mlp2_kernel<<<dim3(NN / 32, 3), 256, 0, stream>>>(
        ori, sm, wpk, b0l, b0s, b0h, b1l, b1s, b1h, amp, ahp,
        out, emb, ut, ehi, elo, uphi, uplo);
    colsum_kernel<<<64, 256, 0, stream>>>(ut, colsum);
    max5_kernel<<<dim3(96, 96), 256, 0, stream>>>(uphi, uplo, mx);
    finalize_kernel<<<1, 64, 0, stream>>>(colsum, mx, scal);
    prop6_kernel<<<dim3(NN / 32, 8), 256, 0, stream>>>(
        uphi, uplo, ehi, elo, scal, ahp, part);
    combine4_kernel<<<NN / 16, 256, 0, stream>>>(
        part, emb, ahp, out + (size_t)2 * NN * DOUT);
}

// Round 14
// 159.289 us; speedup vs baseline: 1.6313x; 1.0796x over previous
//
#include <hip/hip_runtime.h>
#include <hip/hip_bf16.h>

#define NN 6144
#define FEATN 128
#define INSM 512
#define HIDN 256
#define DOUT 64

typedef _Float16 h4v __attribute__((ext_vector_type(4)));
typedef _Float16 h8v __attribute__((ext_vector_type(8)));
typedef float f32x4 __attribute__((ext_vector_type(4)));

// Weight-pack offsets (in halves) inside the contiguous wpk buffer.
#define O_W0L 0
#define O_W0S 65536
#define O_W0H 327680
#define O_W1L 589824
#define O_W1S 622592
#define O_W1H 655360
#define WPK_HALVES 688128
// X-pack offsets (halves) inside xpk: ori hi/lo then sm hi/lo.
#define XO_ORI 0
#define XO_SM  1572864          // 2 * 128 * 6144
#define XPK_HALVES 7864320      // + 2 * 512 * 6144

// ---------------------------------------------------------------------------
// Pack weights (ids 0-5) and X matrices (id 6 = ori, id 7 = sm) to fp16
// hi/lo in MFMA fragment k-major layout. Also zeroes mx (block 0).
// ---------------------------------------------------------------------------
__global__ __launch_bounds__(256) void pack_all_kernel(
    const float* __restrict__ W0l, const float* __restrict__ W0s_,
    const float* __restrict__ W0h, const float* __restrict__ W1l,
    const float* __restrict__ W1s_, const float* __restrict__ W1h,
    const float* __restrict__ ori, const float* __restrict__ sm,
    _Float16* __restrict__ pk, _Float16* __restrict__ xpk,
    unsigned int* __restrict__ mx)
{
    const int t = threadIdx.x;
    if (blockIdx.x == 0 && blockIdx.y == 0 && t == 0) mx[0] = 0u;
    const int id = blockIdx.y;
    const int idx = blockIdx.x * 256 + t;
    if (id < 6) {
        const float* src; int K, N, offhi;
        switch (id) {
            case 0:  src = W0l;  K = 128; N = 256; offhi = O_W0L; break;
            case 1:  src = W0s_; K = 512; N = 256; offhi = O_W0S; break;
            case 2:  src = W0h;  K = 512; N = 256; offhi = O_W0H; break;
            case 3:  src = W1l;  K = 256; N = 64;  offhi = O_W1L; break;
            case 4:  src = W1s_; K = 256; N = 64;  offhi = O_W1S; break;
            default: src = W1h;  K = 256; N = 64;  offhi = O_W1H; break;
        }
        const int cnt = (K * N) >> 3;
        if (idx >= cnt) return;
        const int col  = (N == 256) ? (idx & 255) : (idx & 63);
        const int kblk = (N == 256) ? (idx >> 8) : (idx >> 6);
        h8v hi, lo;
        #pragma unroll
        for (int e = 0; e < 8; ++e) {
            float x = src[(size_t)(kblk * 8 + e) * N + col];
            _Float16 h = (_Float16)x;
            hi[e] = h;
            lo[e] = (_Float16)(x - (float)h);
        }
        *reinterpret_cast<h8v*>(&pk[(size_t)offhi + (size_t)idx * 8]) = hi;
        *reinterpret_cast<h8v*>(&pk[(size_t)offhi + (size_t)(K * N) + (size_t)idx * 8]) = lo;
    } else {
        const float* Xs = (id == 6) ? ori : sm;
        const int K = (id == 6) ? FEATN : INSM;
        const int cnt = NN * (K >> 3);
        if (idx >= cnt) return;
        const int i = idx % NN, kblk = idx / NN;
        const float* p = &Xs[(size_t)i * K + kblk * 8];
        float4 a = *reinterpret_cast<const float4*>(p);
        float4 b = *reinterpret_cast<const float4*>(p + 4);
        float fv[8] = {a.x, a.y, a.z, a.w, b.x, b.y, b.z, b.w};
        h8v hi, lo;
        #pragma unroll
        for (int e = 0; e < 8; ++e) {
            _Float16 h = (_Float16)fv[e];
            hi[e] = h;
            lo[e] = (_Float16)(fv[e] - (float)h);
        }
        _Float16* xh = xpk + ((id == 6) ? XO_ORI : XO_SM);
        _Float16* xl = xh + (size_t)K * NN;
        *reinterpret_cast<h8v*>(&xh[(size_t)idx * 8]) = hi;   // idx = kblk*NN + i
        *reinterpret_cast<h8v*>(&xl[(size_t)idx * 8]) = lo;
    }
}

// ---------------------------------------------------------------------------
// MFMA MLP v3: layer-1 A-fragments DIRECT from pre-packed xpk (no LDS
// staging, no barriers, no per-step cvt). Layer-2 via hs LDS (proven).
// br==2 epilogue: softmax+normalize -> emb; packs ehi/elo + uphi/uplo;
// per-block f64 column partials -> colpart (replaces colsum kernel).
// ---------------------------------------------------------------------------
__global__ __launch_bounds__(256) void mlp3_kernel(
    const _Float16* __restrict__ xpk, const _Float16* __restrict__ pk,
    const float* __restrict__ b0l, const float* __restrict__ b0s,
    const float* __restrict__ b0h, const float* __restrict__ b1l,
    const float* __restrict__ b1s, const float* __restrict__ b1h,
    const float* __restrict__ am_p, const float* __restrict__ ah_p,
    float* __restrict__ out, float* __restrict__ emb,
    _Float16* __restrict__ ehi, _Float16* __restrict__ elo,
    _Float16* __restrict__ uphi, _Float16* __restrict__ uplo,
    double* __restrict__ colpart)
{
    __shared__ __align__(16) char smem[32 * 264 * 4];   // 33792 B
    float* hs    = (float*)smem;            // [32][264] (layer2)
    float* vals  = (float*)smem;            // [32][65] logits (br2)
    float* uvals = (float*)(smem + 16384);  // [32][65] u rows (br2)
    double* cred = (double*)(smem + 24704); // [4][64] colsum partials (br2)

    const int t = threadIdx.x;
    const int br = blockIdx.y;
    const int r0 = blockIdx.x * 32;
    const int w = t >> 6, lane = t & 63, arow = lane & 15, ag = lane >> 4;

    const _Float16 *Ahi, *Alo, *B0hi, *B0lo, *B1hi, *B1lo;
    const float *bias0, *bias1;
    int K1; float alpha;
    if (br == 0) {
        Ahi = xpk + XO_ORI; Alo = Ahi + 128 * NN;
        B0hi = pk + O_W0L; B0lo = B0hi + 128 * 256;
        B1hi = pk + O_W1L; B1lo = B1hi + 256 * 64;
        bias0 = b0l; bias1 = b1l; K1 = FEATN; alpha = am_p[0];
    } else if (br == 1) {
        Ahi = xpk + XO_SM; Alo = Ahi + 512 * NN;
        B0hi = pk + O_W0S; B0lo = B0hi + 512 * 256;
        B1hi = pk + O_W1S; B1lo = B1hi + 256 * 64;
        bias0 = b0s; bias1 = b1s; K1 = INSM; alpha = am_p[0];
    } else {
        Ahi = xpk + XO_SM; Alo = Ahi + 512 * NN;
        B0hi = pk + O_W0H; B0lo = B0hi + 512 * 256;
        B1hi = pk + O_W1H; B1lo = B1hi + 256 * 64;
        bias0 = b0h; bias1 = b1h; K1 = INSM; alpha = ah_p[0];
    }
    const int nks = K1 >> 5;

    // ---- layer 1: H[32][256] = prelu(X@W0 + b0), fragments from global ----
    f32x4 acc1[2][4] = {};
    for (int ks = 0; ks < nks; ++ks) {
        h8v ahi[2], alo8[2];
        #pragma unroll
        for (int rt = 0; rt < 2; ++rt) {
            const size_t ao = ((size_t)(ks * 4 + ag) * NN + r0 + rt * 16 + arow) * 8;
            ahi[rt]  = *reinterpret_cast<const h8v*>(&Ahi[ao]);
            alo8[rt] = *reinterpret_cast<const h8v*>(&Alo[ao]);
        }
        #pragma unroll
        for (int ct = 0; ct < 4; ++ct) {
            const size_t bidx =
                ((size_t)(ks * 4 + ag) * 256 + w * 64 + ct * 16 + arow) * 8;
            h8v bhi = *reinterpret_cast<const h8v*>(&B0hi[bidx]);
            h8v blo = *reinterpret_cast<const h8v*>(&B0lo[bidx]);
            #pragma unroll
            for (int rt = 0; rt < 2; ++rt) {
                acc1[rt][ct] = __builtin_amdgcn_mfma_f32_16x16x32_f16(ahi[rt], bhi, acc1[rt][ct], 0, 0, 0);
                acc1[rt][ct] = __builtin_amdgcn_mfma_f32_16x16x32_f16(ahi[rt], blo, acc1[rt][ct], 0, 0, 0);
                acc1[rt][ct] = __builtin_amdgcn_mfma_f32_16x16x32_f16(alo8[rt], bhi, acc1[rt][ct], 0, 0, 0);
            }
        }
    }

    // epilogue L1: bias + prelu -> hs
    #pragma unroll
    for (int ct = 0; ct < 4; ++ct) {
        const int col = w * 64 + ct * 16 + arow;
        const float bb = bias0[col];
        #pragma unroll
        for (int rt = 0; rt < 2; ++rt)
            #pragma unroll
            for (int r = 0; r < 4; ++r) {
                float h = acc1[rt][ct][r] + bb;
                hs[(rt * 16 + ag * 4 + r) * 264 + col] = (h >= 0.f) ? h : alpha * h;
            }
    }
    __syncthreads();

    // ---- layer 2: O[32][64] = H@W1 + b1 (K=256, 8 K-steps) ----
    f32x4 acc2[2] = {};
    #pragma unroll
    for (int ks2 = 0; ks2 < 8; ++ks2) {
        const size_t bidx = ((size_t)(ks2 * 4 + ag) * 64 + w * 16 + arow) * 8;
        h8v bhi = *reinterpret_cast<const h8v*>(&B1hi[bidx]);
        h8v blo = *reinterpret_cast<const h8v*>(&B1lo[bidx]);
        #pragma unroll
        for (int rt = 0; rt < 2; ++rt) {
            const float* ap = &hs[(rt * 16 + arow) * 264 + ks2 * 32 + ag * 8];
            float4 a = *reinterpret_cast<const float4*>(ap);
            float4 b = *reinterpret_cast<const float4*>(ap + 4);
            float fv[8] = {a.x, a.y, a.z, a.w, b.x, b.y, b.z, b.w};
            h8v ahi8, alo8;
            #pragma unroll
            for (int e = 0; e < 8; ++e) {
                _Float16 h = (_Float16)fv[e];
                ahi8[e] = h;
                alo8[e] = (_Float16)(fv[e] - (float)h);
            }
            acc2[rt] = __builtin_amdgcn_mfma_f32_16x16x32_f16(ahi8, bhi, acc2[rt], 0, 0, 0);
            acc2[rt] = __builtin_amdgcn_mfma_f32_16x16x32_f16(ahi8, blo, acc2[rt], 0, 0, 0);
            acc2[rt] = __builtin_amdgcn_mfma_f32_16x16x32_f16(alo8, bhi, acc2[rt], 0, 0, 0);
        }
    }

    const int col2 = w * 16 + arow;
    const float bb1 = bias1[col2];
    if (br < 2) {
        float* dst = out + (size_t)br * NN * DOUT;
        #pragma unroll
        for (int rt = 0; rt < 2; ++rt)
            #pragma unroll
            for (int r = 0; r < 4; ++r)
                dst[(size_t)(r0 + rt * 16 + ag * 4 + r) * 64 + col2] =
                    acc2[rt][r] + bb1;
    } else {
        __syncthreads();                        // hs reads done; vals aliases
        #pragma unroll
        for (int rt = 0; rt < 2; ++rt)
            #pragma unroll
            for (int r = 0; r < 4; ++r)
                vals[(rt * 16 + ag * 4 + r) * 65 + col2] = acc2[rt][r] + bb1;
        __syncthreads();
        // row softmax + L2 normalize; wave w owns rows w*8..+7
        double myc = 0.0;
        for (int rr = 0; rr < 8; ++rr) {
            const int row = w * 8 + rr;
            float v = vals[row * 65 + lane];
            float mv = v;
            for (int off = 32; off > 0; off >>= 1) mv = fmaxf(mv, __shfl_xor(mv, off));
            float e = expf(v - mv);
            float ssum = e;
            for (int off = 32; off > 0; off >>= 1) ssum += __shfl_xor(ssum, off);
            float s = e / ssum;
            float n2 = s * s;
            for (int off = 32; off > 0; off >>= 1) n2 += __shfl_xor(n2, off);
            float uu = s * rsqrtf(n2);    // d_i >= 1/64 so max(.,1e-9) never binds
            emb[(size_t)(r0 + row) * 64 + lane] = v;
            uvals[row * 65 + lane] = uu;
            myc += (double)uu;
        }
        cred[w * 64 + lane] = myc;
        __syncthreads();                        // uvals + cred ready; vals intact
        {   // pack ehi/elo from vals
            const int jb = t >> 6, c = t & 63;
            h8v hi, lo;
            #pragma unroll
            for (int e = 0; e < 8; ++e) {
                float x = vals[(jb * 8 + e) * 65 + c];
                _Float16 h = (_Float16)x;
                hi[e] = h;
                lo[e] = (_Float16)(x - (float)h);
            }
            const size_t o = ((size_t)(r0 / 8 + jb) * 64 + c) * 8;
            *reinterpret_cast<h8v*>(&ehi[o]) = hi;
            *reinterpret_cast<h8v*>(&elo[o]) = lo;
        }
        {   // pack uphi/uplo from uvals
            const int kb = t >> 5, i = t & 31;
            h8v hi, lo;
            #pragma unroll
            for (int e = 0; e < 8; ++e) {
                float x = uvals[i * 65 + kb * 8 + e];
                _Float16 h = (_Float16)x;
                hi[e] = h;
                lo[e] = (_Float16)(x - (float)h);
            }
            const size_t o = ((size_t)kb * NN + r0 + i) * 8;
            *reinterpret_cast<h8v*>(&uphi[o]) = hi;
            *reinterpret_cast<h8v*>(&uplo[o]) = lo;
        }
        if (t < 64) {   // per-block column partial (fixed order -> deterministic)
            double cs = cred[t] + cred[64 + t] + cred[128 + t] + cred[192 + t];
            colpart[(size_t)blockIdx.x * 64 + t] = cs;
        }
    }
}

// ---------------------------------------------------------------------------
// MFMA max pass: max_{i!=j} R_ij, upper triangle (proven round 12).
// ---------------------------------------------------------------------------
__global__ __launch_bounds__(256) void max5_kernel(
    const _Float16* __restrict__ uphi, const _Float16* __restrict__ uplo,
    unsigned int* __restrict__ mx)
{
    const int ti = blockIdx.x, tj = blockIdx.y;
    if (tj < ti) return;
    __shared__ float red[4];
    const int t = threadIdx.x;
    const int w = t >> 6, l = t & 63, arow = l & 15, ag = l >> 4;
    f32x4 acc[4] = {};
    #pragma unroll
    for (int ks = 0; ks < 2; ++ks) {
        const size_t bo = ((size_t)(ks * 4 + ag) * NN + tj * 64 + w * 16 + arow) * 8;
        h8v bhi = *reinterpret_cast<const h8v*>(&uphi[bo]);
        h8v blo = *reinterpret_cast<const h8v*>(&uplo[bo]);
        #pragma unroll
        for (int rt = 0; rt < 4; ++rt) {
            const size_t ao = ((size_t)(ks * 4 + ag) * NN + ti * 64 + rt * 16 + arow) * 8;
            h8v ahi_ = *reinterpret_cast<const h8v*>(&uphi[ao]);
            h8v alo_ = *reinterpret_cast<const h8v*>(&uplo[ao]);
            acc[rt] = __builtin_amdgcn_mfma_f32_16x16x32_f16(ahi_, bhi, acc[rt], 0, 0, 0);
            acc[rt] = __builtin_amdgcn_mfma_f32_16x16x32_f16(ahi_, blo, acc[rt], 0, 0, 0);
            acc[rt] = __builtin_amdgcn_mfma_f32_16x16x32_f16(alo_, bhi, acc[rt], 0, 0, 0);
        }
    }
    float lm = 0.f;
    const int gj = tj * 64 + w * 16 + arow;
    #pragma unroll
    for (int rt = 0; rt < 4; ++rt)
        #pragma unroll
        for (int r = 0; r < 4; ++r) {
            const int gi = ti * 64 + rt * 16 + ag * 4 + r;
            if (gi != gj) lm = fmaxf(lm, acc[rt][r]);
        }
    for (int off = 32; off > 0; off >>= 1) lm = fmaxf(lm, __shfl_xor(lm, off));
    if ((t & 63) == 0) red[t >> 6] = lm;
    __syncthreads();
    if (t == 0) {
        float bm = fmaxf(fmaxf(red[0], red[1]), fmaxf(red[2], red[3]));
        atomicMax(mx, __float_as_uint(bm));
    }
}

__global__ void finalize_kernel(const double* __restrict__ colpart,
                                const unsigned int* __restrict__ mx,
                                float* __restrict__ scal)
{
    const int c = threadIdx.x;   // 64 threads = 1 wave
    double cs = 0.0;
    for (int b = 0; b < 192; ++b) cs += colpart[(size_t)b * 64 + c];
    double s2 = cs * cs;
    for (int off = 32; off > 0; off >>= 1) s2 += __shfl_xor(s2, off);
    if (c == 0) {
        double md = (s2 - (double)NN) / ((double)NN * (double)NN);
        float mf = (float)md;
        float mxv = __uint_as_float(mx[0]);
        scal[0] = mf;
        scal[1] = 1.0f / (mxv - mf);
        scal[2] = 1.0f / mf;
    }
}

// ---------------------------------------------------------------------------
// Fused propagation v6 (proven round 13): 32 i-rows/block, grid (192, 8).
// ---------------------------------------------------------------------------
__global__ __launch_bounds__(256, 4) void prop6_kernel(
    const _Float16* __restrict__ uphi, const _Float16* __restrict__ uplo,
    const _Float16* __restrict__ ehi, const _Float16* __restrict__ elo,
    const float* __restrict__ scal, const float* __restrict__ ah_p,
    float* __restrict__ part)
{
    __shared__ __align__(16) _Float16 Abuf[2][2][32 * 128];  // 32 KB

    const int t = threadIdx.x;
    const int bi = blockIdx.x;
    const int q = blockIdx.y;
    const int gi0 = bi * 32;
    const float m = scal[0], inv_pd = scal[1], inv_m = scal[2];
    const float alpha = ah_p[0];

    const int w = t >> 6, l = t & 63, arow = l & 15, ag = l >> 4;
    const int col = w * 16 + arow;

    h8v ubhi[2][2], ublo[2][2];              // [ks][ih]
    #pragma unroll
    for (int ks = 0; ks < 2; ++ks)
        #pragma unroll
        for (int ih = 0; ih < 2; ++ih) {
            const size_t o = ((size_t)(ks * 4 + ag) * NN + gi0 + ih * 16 + arow) * 8;
            ubhi[ks][ih] = *reinterpret_cast<const h8v*>(&uphi[o]);
            ublo[ks][ih] = *reinterpret_cast<const h8v*>(&uplo[o]);
        }

    f32x4 accP[2] = {};
    f32x4 accL[2] = {};

    const int jt0 = q * 6, jt1 = jt0 + 6;
    for (int jt = jt0; jt < jt1; ++jt) {
        const int buf = jt & 1;
        char* base = (char*)&Abuf[buf][0][0];
        #pragma unroll
        for (int ff = 0; ff < 2; ++ff) {
            const int f = w * 2 + ff;
            const int j0 = jt * 128 + f * 16;
            h8v jh0, jl0, jh1, jl1;
            {
                const size_t o0 = ((size_t)ag * NN + j0 + arow) * 8;
                jh0 = *reinterpret_cast<const h8v*>(&uphi[o0]);
                jl0 = *reinterpret_cast<const h8v*>(&uplo[o0]);
                const size_t o1 = ((size_t)(4 + ag) * NN + j0 + arow) * 8;
                jh1 = *reinterpret_cast<const h8v*>(&uphi[o1]);
                jl1 = *reinterpret_cast<const h8v*>(&uplo[o1]);
            }
            #pragma unroll
            for (int ih = 0; ih < 2; ++ih) {
                f32x4 aR0 = {0.f, 0.f, 0.f, 0.f};
                f32x4 aR1 = {0.f, 0.f, 0.f, 0.f};
                aR0 = __builtin_amdgcn_mfma_f32_16x16x32_f16(jh0, ubhi[0][ih], aR0, 0, 0, 0);
                aR0 = __builtin_amdgcn_mfma_f32_16x16x32_f16(jh0, ublo[0][ih], aR0, 0, 0, 0);
                aR0 = __builtin_amdgcn_mfma_f32_16x16x32_f16(jl0, ubhi[0][ih], aR0, 0, 0, 0);
                aR1 = __builtin_amdgcn_mfma_f32_16x16x32_f16(jh1, ubhi[1][ih], aR1, 0, 0, 0);
                aR1 = __builtin_amdgcn_mfma_f32_16x16x32_f16(jh1, ublo[1][ih], aR1, 0, 0, 0);
                aR1 = __builtin_amdgcn_mfma_f32_16x16x32_f16(jl1, ubhi[1][ih], aR1, 0, 0, 0);
                const int gi = gi0 + ih * 16 + arow;
                h4v vh4, ph4;
                #pragma unroll
                for (int r = 0; r < 4; ++r) {
                    const int gj = j0 + ag * 4 + r;
                    float rv = aR0[r] + aR1[r];
                    float lre = (gi == gj) ? 0.f : rv;
                    float x = lre - m;
                    float v = (x > 0.f) ? x * inv_pd : -(lre * inv_m);
                    if (gi == gj) v += 1.f;          // add_diag after where
                    float p = (v >= 0.f) ? v : alpha * v;
                    vh4[r] = (_Float16)v;
                    ph4[r] = (_Float16)p;
                }
                const int gl = f * 2 + (ag >> 1);
                const int byte = (ih * 16 + arow) * 256 +
                                 ((gl ^ (arow & 15)) << 4) + ((ag & 1) << 3);
                *reinterpret_cast<h4v*>(base + byte) = vh4;
                *reinterpret_cast<h4v*>(base + 8192 + byte) = ph4;
            }
        }
        __syncthreads();        // single barrier per tile (dbuf-safe)

        const char* cbase = (const char*)&Abuf[buf][0][0];
        __builtin_amdgcn_s_setprio(1);
        #pragma unroll
        for (int ks = 0; ks < 4; ++ks) {
            const size_t bidx = ((size_t)(jt * 16 + ks * 4 + ag) * 64 + col) * 8;
            h8v Bhi = *reinterpret_cast<const h8v*>(&ehi[bidx]);
            h8v Blo = *reinterpret_cast<const h8v*>(&elo[bidx]);
            #pragma unroll
            for (int ih = 0; ih < 2; ++ih) {
                const int abyte = (ih * 16 + arow) * 256 +
                                  (((ks * 4 + ag) ^ (arow & 15)) << 4);
                h8v vhiF = *reinterpret_cast<const h8v*>(cbase + abyte);
                h8v phiF = *reinterpret_cast<const h8v*>(cbase + 8192 + abyte);
                accP[ih] = __builtin_amdgcn_mfma_f32_16x16x32_f16(phiF, Bhi, accP[ih], 0, 0, 0);
                accP[ih] = __builtin_amdgcn_mfma_f32_16x16x32_f16(phiF, Blo, accP[ih], 0, 0, 0);
                accL[ih] = __builtin_amdgcn_mfma_f32_16x16x32_f16(vhiF, Bhi, accL[ih], 0, 0, 0);
                accL[ih] = __builtin_amdgcn_mfma_f32_16x16x32_f16(vhiF, Blo, accL[ih], 0, 0, 0);
            }
        }
        __builtin_amdgcn_s_setprio(0);
    }

    {
        float* pbase = &part[((size_t)q * NN + gi0) * 128];
        #pragma unroll
        for (int ih = 0; ih < 2; ++ih)
            #pragma unroll
            for (int r = 0; r < 4; ++r) {
                const int row = ih * 16 + ag * 4 + r;
                pbase[(size_t)row * 128 + col] = accP[ih][r];
                pbase[(size_t)row * 128 + 64 + col] = accL[ih][r];
            }
    }
}

// ---------------------------------------------------------------------------
// Combine 8 partials: P = sum, L = sum, N = P - (1+alpha)L, dual softmax,
// epilogue -> out3.
// ---------------------------------------------------------------------------
__global__ __launch_bounds__(256) void combine4_kernel(
    const float* __restrict__ part, const float* __restrict__ emb,
    const float* __restrict__ ah_p, float* __restrict__ out3)
{
    const int t = threadIdx.x;
    const int w = t >> 6, l = t & 63;
    const int gi0 = blockIdx.x * 16;
    const float one_pa = 1.f + ah_p[0];
    #pragma unroll
    for (int rr = 0; rr < 4; ++rr) {
        const int gi = gi0 + w * 4 + rr;
        float zp = 0.f, zl = 0.f;
        #pragma unroll
        for (int q = 0; q < 8; ++q) {
            const float* p = &part[((size_t)q * NN + gi) * 128];
            zp += p[l];
            zl += p[64 + l];
        }
        float zn = zp - one_pa * zl;

        float mp = zp;
        for (int off = 32; off > 0; off >>= 1) mp = fmaxf(mp, __shfl_xor(mp, off));
        float ep = __expf(zp - mp);
        float sump = ep;
        for (int off = 32; off > 0; off >>= 1) sump += __shfl_xor(sump, off);
        float pp = ep / sump;

        float mn = zn;
        for (int off = 32; off > 0; off >>= 1) mn = fmaxf(mn, __shfl_xor(mn, off));
        float en = __expf(zn - mn);
        float sumn = en;
        for (int off = 32; off > 0; off >>= 1) sumn += __shfl_xor(sumn, off);
        float pn = en / sumn;

        out3[(size_t)gi * 64 + l] = 0.5f * (pp - pn + emb[(size_t)gi * 64 + l]);
    }
}

extern "C" void kernel_launch(void* const* d_in, const int* in_sizes, int n_in,
                              void* d_out, int out_size, void* d_ws, size_t ws_size,
                              hipStream_t stream)
{
    (void)in_sizes; (void)n_in; (void)out_size; (void)ws_size;
    const float* ori = (const float*)d_in[0];
    const float* sm  = (const float*)d_in[1];
    // d_in[2] processed_feature: unused; d_in[3] universal_re: unused (BETA=0)
    const float* W0s = (const float*)d_in[4];
    const float* b0s = (const float*)d_in[5];
    const float* W1s = (const float*)d_in[6];
    const float* b1s = (const float*)d_in[7];
    const float* W0l = (const float*)d_in[8];
    const float* b0l = (const float*)d_in[9];
    const float* W1l = (const float*)d_in[10];
    const float* b1l = (const float*)d_in[11];
    const float* W0h = (const float*)d_in[12];
    const float* b0h = (const float*)d_in[13];
    const float* W1h = (const float*)d_in[14];
    const float* b1h = (const float*)d_in[15];
    const float* amp = (const float*)d_in[16];
    const float* ahp = (const float*)d_in[17];

    float* out = (float*)d_out;                       // f32 output (ref dtype)
    float* ws = (float*)d_ws;
    float* emb = ws;                                            // 393216 f32
    double* colpart = (double*)(ws + (size_t)NN * DOUT);        // 192*64 f64
    unsigned int* mx = (unsigned int*)(ws + (size_t)NN * DOUT + 24576);
    float* scal = ws + (size_t)NN * DOUT + 24576 + 4;           // 3 f32
    size_t eh_off = (size_t)NN * DOUT + 24576 + 8;              // 16B-aligned
    _Float16* ehi = (_Float16*)(ws + eh_off);                   // NN*64 halves
    _Float16* elo = ehi + (size_t)NN * DOUT;
    size_t up_off = eh_off + (size_t)NN * DOUT;                 // f32 words
    _Float16* uphi = (_Float16*)(ws + up_off);
    _Float16* uplo = uphi + (size_t)NN * DOUT;
    size_t wpk_off = up_off + (size_t)NN * DOUT;
    _Float16* wpk = (_Float16*)(ws + wpk_off);                  // 688128 halves
    size_t sh_off = (wpk_off + WPK_HALVES / 2 + 3) & ~(size_t)3;
    _Float16* xpk = (_Float16*)(ws + sh_off);   // 7864320 halves (mlp phase)
    float* part = ws + sh_off;                  // 8*NN*128 f32 (prop phase)
    // xpk and part alias: xpk dead after mlp3; part born in prop6.
    // total ws footprint ~31.4 MB (<= the 33 MB proven in round 13)

    pack_all_kernel<<<dim3(1536, 8), 256, 0, stream>>>(
        W0l, W0s, W0h, W1l, W1s, W1h, ori, sm, wpk, xpk, mx);
    mlp3_kernel<<<dim3(NN / 32, 3), 256, 0, stream>>>(
        xpk, wpk, b0l, b0s, b0h, b1l, b1s, b1h, amp, ahp,
        out, emb, ehi, elo, uphi, uplo, colpart);
    max5_kernel<<<dim3(96, 96), 256, 0, stream>>>(uphi, uplo, mx);
    finalize_kernel<<<1, 64, 0, stream>>>(colpart, mx, scal);
    prop6_kernel<<<dim3(NN / 32, 8), 256, 0, stream>>>(
        uphi, uplo, ehi, elo, scal, ahp, part);
    combine4_kernel<<<NN / 16, 256, 0, stream>>>(
        part, emb, ahp, out + (size_t)2 * NN * DOUT);
}